// Round 11
// baseline (357.090 us; speedup 1.0000x reference)
//
#include <hip/hip_runtime.h>
#include <hip/hip_bf16.h>
#include <math.h>

#define BB 32
#define SS 512
#define DD 256
#define HH 8
#define HDIM 32
#define FFNN 128
#define NROWS (BB*SS)        // 16384
#define NELEM (NROWS*DD)     // 4194304

using bf16 = __hip_bfloat16;
typedef __attribute__((ext_vector_type(8))) short short8;
typedef __attribute__((ext_vector_type(4))) short short4v;
typedef __attribute__((ext_vector_type(4))) float floatx4;
typedef unsigned int uint_al __attribute__((may_alias));

static __device__ __forceinline__ float bf2f(bf16 x) { return __bfloat162float(x); }
static __device__ __forceinline__ bf16  f2bf(float x) { return __float2bfloat16(x); }
static __device__ __forceinline__ short f2bfs(float x) {
    bf16 b = __float2bfloat16(x);
    return __builtin_bit_cast(short, b);
}

// pack two f32 -> one dword of two bf16 (no builtin on gfx950; RNE rounding, same as f2bf)
static __device__ __forceinline__ unsigned int cvtpk(float a, float b) {
    unsigned int r;
    asm("v_cvt_pk_bf16_f32 %0, %1, %2" : "=v"(r) : "v"(a), "v"(b));
    return r;
}
static __device__ __forceinline__ short4v mk4(unsigned int a, unsigned int b) {
    union { unsigned int u[2]; short4v s; } t;
    t.u[0] = a; t.u[1] = b;
    return t.s;
}
static __device__ __forceinline__ floatx4 mfma16(short4v a, short4v b, floatx4 c) {
#if __has_builtin(__builtin_amdgcn_mfma_f32_16x16x16bf16_1k)
    return __builtin_amdgcn_mfma_f32_16x16x16bf16_1k(a, b, c, 0, 0, 0);
#else
    asm("v_mfma_f32_16x16x16_bf16 %0, %1, %2, %0" : "+v"(c) : "v"(a), "v"(b));
    return c;
#endif
}

// async global->LDS, 16B per lane; dest = wave-uniform base + lane*16
static __device__ __forceinline__ void gld_lds16(const void* g, void* l) {
    __builtin_amdgcn_global_load_lds(
        (const __attribute__((address_space(1))) void*)g,
        (__attribute__((address_space(3))) void*)l, 16, 0, 0);
}

// ---------- v dtype probe (flag zeroed by setup_pack, stream-ordered before this) ----------
__global__ __launch_bounds__(256) void detect_v(const int* __restrict__ v, int* __restrict__ flag) {
    int i = blockIdx.x * 256 + threadIdx.x;
    if (v[2 * i + 1] != 0) atomicOr(flag, 1);
}

// ---------- one-shot setup: all weight packs (f32 -> bf16 [n][k]) + xPos table + flag=0 ----------
#define NQKVG (3*1024*256)           // 786432
#define NWO   (3*256*256)            // 196608
#define NW1   (3*128*256)            // 98304
#define NW2   (3*256*128)            // 98304
#define NXPT  (512*16)               // 8192
#define NSETUP (NQKVG+NWO+NW1+NW2+NXPT)   // 1187840 = 4640*256
__global__ __launch_bounds__(256) void setup_pack(const float* __restrict__ WQ, const float* __restrict__ WK,
                                                  const float* __restrict__ WV, const float* __restrict__ WG,
                                                  const float* __restrict__ WO, const float* __restrict__ w1,
                                                  const float* __restrict__ w2,
                                                  bf16* __restrict__ dQ, bf16* __restrict__ dO,
                                                  bf16* __restrict__ d1, bf16* __restrict__ d2,
                                                  float4* __restrict__ xpt, int* __restrict__ flag) {
    int idx = blockIdx.x * 256 + threadIdx.x;
    if (idx == 0) *flag = 0;     // replaces the init_flag<<<1,1>>> launch
    if (idx < NQKVG) {
        int k = idx & 255, n = (idx >> 8) & 1023, l = idx >> 18;
        int seg = n >> 8, n8 = n & 255;
        float val;
        if (seg < 3) {
            const float* W = (seg == 0) ? WQ : (seg == 1) ? WK : WV;
            int h = n8 >> 5, e = n8 & 31;
            val = W[(((size_t)l * 8 + h) * 256 + k) * 32 + e];
        } else {
            val = WG[(size_t)l * 65536 + k * 256 + n8];
        }
        dQ[((size_t)l * 1024 + n) * 256 + k] = f2bf(val);
    } else if (idx < NQKVG + NWO) {
        int i = idx - NQKVG;
        int k = i & 255, n = (i >> 8) & 255, l = i >> 16;
        dO[((size_t)l * 256 + n) * 256 + k] = f2bf(WO[(size_t)l * 65536 + k * 256 + n]);
    } else if (idx < NQKVG + NWO + NW1) {
        int i = idx - NQKVG - NWO;
        int k = i & 255, n = (i >> 8) & 127, l = i >> 15;
        d1[((size_t)l * 128 + n) * 256 + k] = f2bf(w1[(size_t)l * 32768 + k * 128 + n]);
    } else if (idx < NQKVG + NWO + NW1 + NW2) {
        int i = idx - NQKVG - NWO - NW1;
        int k = i & 127, n = (i >> 7) & 255, l = i >> 15;
        d2[((size_t)l * 256 + n) * 128 + k] = f2bf(w2[(size_t)l * 32768 + k * 256 + n]);
    } else {
        int i = idx - NQKVG - NWO - NW1 - NW2;     // 0..8191
        int jf = i & 15, s = i >> 4;
        float base = (2.0f * jf + 12.8f) / 44.8f;
        float sm = powf(base, (float)s * (1.0f / 512.0f));
        float ang = (float)s * powf(10000.0f, -(float)jf / 16.0f);
        float sn, cs;
        sincosf(ang, &sn, &cs);
        xpt[i] = float4{cs * sm, sn * sm, cs / sm, sn / sm};
    }
}

// ---------- fused embed + LN1(layer0): 8 rows per block (grid 2048) ----------
__global__ __launch_bounds__(256) void embed_ln_kernel(const int* __restrict__ v,
                                                       const float* __restrict__ emb,
                                                       const int* __restrict__ flag,
                                                       const float* __restrict__ w,
                                                       const float* __restrict__ b,
                                                       float* __restrict__ X,
                                                       short* __restrict__ Xn) {
    __shared__ float p1[4], p2[4], st[2];
    const int d = threadIdx.x;
    const int wid = threadIdx.x >> 6;
    const int is32 = *flag;
    const float wd = w[d], bd = b[d];
    for (int it = 0; it < 8; ++it) {
        int row = blockIdx.x * 8 + it;
        int tok = is32 ? v[row] : v[2 * row];
        float x = 0.0f;
        if (tok != 0) {
            x = emb[tok * DD + d];
            x = x > 0.0f ? x : 0.0f;
        }
        X[(size_t)row * DD + d] = x;
        float s1 = x, s2 = x * x;
        #pragma unroll
        for (int off = 1; off < 64; off <<= 1) {
            s1 += __shfl_xor(s1, off);
            s2 += __shfl_xor(s2, off);
        }
        if ((threadIdx.x & 63) == 0) { p1[wid] = s1; p2[wid] = s2; }
        __syncthreads();
        if (threadIdx.x == 0) {
            float t1 = p1[0] + p1[1] + p1[2] + p1[3];
            float t2 = p2[0] + p2[1] + p2[2] + p2[3];
            float mu = t1 * (1.0f / DD);
            float var = t2 * (1.0f / DD) - mu * mu;
            st[0] = mu; st[1] = rsqrtf(var + 1e-5f);
        }
        __syncthreads();
        Xn[(size_t)row * DD + d] = f2bfs((x - st[0]) * st[1] * wd + bd);
    }
}

// ---------- QKVG MFMA GEMM (128x128 tile) ----------
// V segment (cols 512..767) is written TRANSPOSED within each (b, 32-s-chunk, h)
// 32x32 tile: address (s-row = sc*32 + d, col = 512 + h*32 + tr) holds V[s = sc*32+tr][dim d].
// Retention's staging addresses are unchanged (tile internally permuted); its V-fragment
// LDS reads become contiguous b64s instead of 16 scalar u16s (LDS-issue was its bottleneck).
__global__ __launch_bounds__(256) void qkvg_gemm(const short* __restrict__ A,   // Xn, lda=256
                                                 const short* __restrict__ Bp,  // [1024][256] packed
                                                 const float4* __restrict__ xpt,
                                                 bf16* __restrict__ C) {        // ldc=1024
    __shared__ __align__(16) short Als[16 * 512];
    __shared__ __align__(16) short Bls[16 * 512];
    const int tid = threadIdx.x;
    const int wave = tid >> 6, lane = tid & 63, lo = lane & 15, quad = lane >> 4;
    const int wm = wave >> 1, wn = wave & 1;
    const int row0 = blockIdx.x * 128, col0 = blockIdx.y * 128;

    floatx4 acc[4][4];
    #pragma unroll
    for (int i = 0; i < 4; ++i)
        #pragma unroll
        for (int j = 0; j < 4; ++j) acc[i][j] = floatx4{0.f, 0.f, 0.f, 0.f};

    for (int k0 = 0; k0 < 256; k0 += 64) {
        #pragma unroll
        for (int t = 0; t < 4; ++t) {
            int grp = (wm * 4 + t) * 2 + wn;
            const short* ga = A + (size_t)(row0 + (wm * 4 + t) * 16 + lo) * 256
                            + k0 + (wn * 4 + quad) * 8;
            gld_lds16(ga, &Als[grp * 512]);
        }
        #pragma unroll
        for (int t = 0; t < 4; ++t) {
            int grp = (wn * 4 + t) * 2 + wm;
            const short* gb = Bp + (size_t)(col0 + (wn * 4 + t) * 16 + lo) * 256
                            + k0 + (wm * 4 + quad) * 8;
            gld_lds16(gb, &Bls[grp * 512]);
        }
        __syncthreads();
        #pragma unroll
        for (int kkgrp = 0; kkgrp < 2; ++kkgrp) {
            short8 af[4], bfr[4];
            #pragma unroll
            for (int t = 0; t < 4; ++t)
                af[t] = *(const short8*)(&Als[((wm * 4 + t) * 2 + kkgrp) * 512 + lane * 8]);
            #pragma unroll
            for (int t = 0; t < 4; ++t)
                bfr[t] = *(const short8*)(&Bls[((wn * 4 + t) * 2 + kkgrp) * 512 + lane * 8]);
            #pragma unroll
            for (int ti = 0; ti < 4; ++ti)
                #pragma unroll
                for (int tj = 0; tj < 4; ++tj)
                    acc[ti][tj] = __builtin_amdgcn_mfma_f32_16x16x32_bf16(af[ti], bfr[tj], acc[ti][tj], 0, 0, 0);
        }
        __syncthreads();
    }

    short* Cs = (short*)C;
    #pragma unroll
    for (int ti = 0; ti < 4; ++ti) {
        #pragma unroll
        for (int tj = 0; tj < 4; ++tj) {
            int colb = col0 + (wn * 4 + tj) * 16 + lo;
            int seg = colb >> 8;
            if (seg == 2) {
                // V: transposed-in-tile packed store (r=0..3 are 4 consecutive tr, never
                // crossing a 32-boundary since tr base is 4-aligned)
                int rowA = row0 + (wm * 4 + ti) * 16 + quad * 4;
                int bbase = rowA & ~511;
                int sc = (rowA & 511) >> 5;
                int tr = rowA & 31;
                int d  = colb & 31;
                int hh = (colb >> 5) & 7;
                short4v pk = mk4(cvtpk(acc[ti][tj][0], acc[ti][tj][1]),
                                 cvtpk(acc[ti][tj][2], acc[ti][tj][3]));
                *(short4v*)(Cs + (size_t)(bbase + sc * 32 + d) * 1024 + 512 + hh * 32 + tr) = pk;
            } else {
                #pragma unroll
                for (int r = 0; r < 4; ++r) {
                    int row = row0 + (wm * 4 + ti) * 16 + quad * 4 + r;
                    float v = acc[ti][tj][r];
                    if (seg < 2) {
                        int s = row & (SS - 1);
                        int jf = (colb & 31) >> 1;
                        float4 t = xpt[s * 16 + jf];
                        float cs = (seg == 0) ? t.x : t.z;
                        float sn = (seg == 0) ? t.y : t.w;
                        float p = __shfl_xor(v, 1);
                        v = (lo & 1) ? (v * cs + p * sn) : (v * cs - p * sn);
                    }
                    C[(size_t)row * 1024 + colb] = f2bf(v);
                }
            }
        }
    }
}

// ---------- fused WO + FFN (direct-load, barrier-light; r10-proven) ----------
#define HS2 264    // Hn row stride (shorts)
#define HSTR 136   // Hf row stride (shorts)
template<int DOLN>
__global__ __launch_bounds__(256) void wo_ffn_fused(const short* __restrict__ A,     // T in QKVG, lda=1024
                                                    const short* __restrict__ Wo,    // [256][256]
                                                    const short* __restrict__ W1p,   // [128][256]
                                                    const float* __restrict__ b1,
                                                    const short* __restrict__ W2p,   // [256][128]
                                                    const float* __restrict__ b2,
                                                    float* __restrict__ X,
                                                    const float* __restrict__ ln2w,
                                                    const float* __restrict__ ln2b,
                                                    const float* __restrict__ ln1w,
                                                    const float* __restrict__ ln1b,
                                                    short* __restrict__ Xn) {
    __shared__ __align__(16) short Hn[32 * HS2];        // 16.5 KB
    __shared__ __align__(16) short Hf[32 * HSTR];       // 8.5 KB
    __shared__ float Ssum[32][4], Ssq[32][4];           // 1 KB
    const int tid = threadIdx.x;
    const int wave = tid >> 6, lane = tid & 63, lo = lane & 15, quad = lane >> 4;
    const int row0 = blockIdx.x * 32;
    const int colw0 = wave * 64;
    const int kq = quad * 8;

    // ================= phase W: acc = T @ WO, K=256 (all direct, barrier-free) =========
    floatx4 acc[2][4];
    #pragma unroll
    for (int i = 0; i < 2; ++i)
        #pragma unroll
        for (int j = 0; j < 4; ++j) acc[i][j] = floatx4{0.f, 0.f, 0.f, 0.f};

    for (int k0 = 0; k0 < 256; k0 += 64) {
        #pragma unroll
        for (int kk = 0; kk < 2; ++kk) {
            const int kof = k0 + kk * 32 + kq;
            short8 af[2], bfr[4];
            #pragma unroll
            for (int t = 0; t < 2; ++t)
                af[t] = *(const short8*)(A + (size_t)(row0 + t * 16 + lo) * 1024 + kof);
            #pragma unroll
            for (int t = 0; t < 4; ++t)
                bfr[t] = *(const short8*)(Wo + (size_t)(colw0 + t * 16 + lo) * 256 + kof);
            #pragma unroll
            for (int ti = 0; ti < 2; ++ti)
                #pragma unroll
                for (int tj = 0; tj < 4; ++tj)
                    acc[ti][tj] = __builtin_amdgcn_mfma_f32_16x16x32_bf16(af[ti], bfr[tj], acc[ti][tj], 0, 0, 0);
        }
    }

    // Y = X + acc (kept in regs); LN2 -> Hn (LDS)
    float vv[2][4][4];
    #pragma unroll
    for (int ti = 0; ti < 2; ++ti)
        #pragma unroll
        for (int tj = 0; tj < 4; ++tj) {
            int colb = colw0 + tj * 16 + lo;
            #pragma unroll
            for (int r = 0; r < 4; ++r) {
                int row = row0 + ti * 16 + quad * 4 + r;
                vv[ti][tj][r] = acc[ti][tj][r] + X[(size_t)row * DD + colb];
            }
        }
    #pragma unroll
    for (int ti = 0; ti < 2; ++ti)
        #pragma unroll
        for (int r = 0; r < 4; ++r) {
            float s1 = 0.f, s2 = 0.f;
            #pragma unroll
            for (int tj = 0; tj < 4; ++tj) {
                float v = vv[ti][tj][r];
                s1 += v; s2 += v * v;
            }
            #pragma unroll
            for (int off = 1; off < 16; off <<= 1) {
                s1 += __shfl_xor(s1, off);
                s2 += __shfl_xor(s2, off);
            }
            if (lo == 0) {
                int rl = ti * 16 + quad * 4 + r;
                Ssum[rl][wave] = s1;
                Ssq[rl][wave] = s2;
            }
        }
    __syncthreads();
    #pragma unroll
    for (int ti = 0; ti < 2; ++ti)
        #pragma unroll
        for (int r = 0; r < 4; ++r) {
            int rl = ti * 16 + quad * 4 + r;
            float t1 = Ssum[rl][0] + Ssum[rl][1] + Ssum[rl][2] + Ssum[rl][3];
            float t2 = Ssq[rl][0] + Ssq[rl][1] + Ssq[rl][2] + Ssq[rl][3];
            float mu = t1 * (1.0f / DD);
            float var = t2 * (1.0f / DD) - mu * mu;
            float rs = rsqrtf(var + 1e-5f);
            #pragma unroll
            for (int tj = 0; tj < 4; ++tj) {
                int colb = colw0 + tj * 16 + lo;
                Hn[rl * HS2 + colb] =
                    f2bfs((vv[ti][tj][r] - mu) * rs * ln2w[colb] + ln2b[colb]);
            }
        }
    __syncthreads();   // Hn complete before phase-1 reads

    // ================= phase 1: a1 = Hn @ w1, K=256 (A from LDS, B direct) =============
    floatx4 a1[2][2];
    #pragma unroll
    for (int i = 0; i < 2; ++i) { a1[i][0] = floatx4{0,0,0,0}; a1[i][1] = floatx4{0,0,0,0}; }
    for (int k0 = 0; k0 < 256; k0 += 64) {
        #pragma unroll
        for (int kk = 0; kk < 2; ++kk) {
            const int kof = k0 + kk * 32 + kq;
            short8 af[2], bfr[2];
            #pragma unroll
            for (int t = 0; t < 2; ++t)
                af[t] = *(const short8*)(&Hn[(t * 16 + lo) * HS2 + kof]);
            #pragma unroll
            for (int t = 0; t < 2; ++t)
                bfr[t] = *(const short8*)(W1p + (size_t)(wave * 32 + t * 16 + lo) * 256 + kof);
            #pragma unroll
            for (int ti = 0; ti < 2; ++ti)
                #pragma unroll
                for (int tj = 0; tj < 2; ++tj)
                    a1[ti][tj] = __builtin_amdgcn_mfma_f32_16x16x32_bf16(af[ti], bfr[tj], a1[ti][tj], 0, 0, 0);
        }
    }
    // gelu -> Hf
    #pragma unroll
    for (int ti = 0; ti < 2; ++ti)
        #pragma unroll
        for (int tj = 0; tj < 2; ++tj) {
            int colb = wave * 32 + tj * 16 + lo;
            float bs = b1[colb];
            #pragma unroll
            for (int r = 0; r < 4; ++r) {
                int rl = ti * 16 + quad * 4 + r;
                float v = a1[ti][tj][r] + bs;
                v = 0.5f * v * (1.0f + erff(v * 0.70710678118f));
                Hf[rl * HSTR + colb] = f2bfs(v);
            }
        }
    __syncthreads();   // Hf complete before phase-2 reads

    // ================= phase 2: a2 = Hf @ w2, K=128 (A from LDS, B direct) =============
    floatx4 a2[2][4];
    #pragma unroll
    for (int i = 0; i < 2; ++i)
        #pragma unroll
        for (int j = 0; j < 4; ++j) a2[i][j] = floatx4{0,0,0,0};
    for (int k0 = 0; k0 < 128; k0 += 64) {
        #pragma unroll
        for (int kk = 0; kk < 2; ++kk) {
            const int kof = k0 + kk * 32 + kq;
            short8 af[2], bfr[4];
            #pragma unroll
            for (int t = 0; t < 2; ++t)
                af[t] = *(const short8*)(&Hf[(t * 16 + lo) * HSTR + kof]);
            #pragma unroll
            for (int t = 0; t < 4; ++t)
                bfr[t] = *(const short8*)(W2p + (size_t)(colw0 + t * 16 + lo) * 128 + kof);
            #pragma unroll
            for (int ti = 0; ti < 2; ++ti)
                #pragma unroll
                for (int tj = 0; tj < 4; ++tj)
                    a2[ti][tj] = __builtin_amdgcn_mfma_f32_16x16x32_bf16(af[ti], bfr[tj], a2[ti][tj], 0, 0, 0);
        }
    }

    // ================= final: X = Y + FFN; opt LN1_next -> Xn =================
    #pragma unroll
    for (int ti = 0; ti < 2; ++ti)
        #pragma unroll
        for (int tj = 0; tj < 4; ++tj) {
            int colb = colw0 + tj * 16 + lo;
            float bs = b2[colb];
            #pragma unroll
            for (int r = 0; r < 4; ++r) {
                int row = row0 + ti * 16 + quad * 4 + r;
                float v = a2[ti][tj][r] + bs + vv[ti][tj][r];
                X[(size_t)row * DD + colb] = v;
                vv[ti][tj][r] = v;
            }
        }
    if (!DOLN) return;
    #pragma unroll
    for (int ti = 0; ti < 2; ++ti)
        #pragma unroll
        for (int r = 0; r < 4; ++r) {
            float s1 = 0.f, s2 = 0.f;
            #pragma unroll
            for (int tj = 0; tj < 4; ++tj) {
                float v = vv[ti][tj][r];
                s1 += v; s2 += v * v;
            }
            #pragma unroll
            for (int off = 1; off < 16; off <<= 1) {
                s1 += __shfl_xor(s1, off);
                s2 += __shfl_xor(s2, off);
            }
            if (lo == 0) {
                int rl = ti * 16 + quad * 4 + r;
                Ssum[rl][wave] = s1;
                Ssq[rl][wave] = s2;
            }
        }
    __syncthreads();
    #pragma unroll
    for (int ti = 0; ti < 2; ++ti)
        #pragma unroll
        for (int r = 0; r < 4; ++r) {
            int rl = ti * 16 + quad * 4 + r;
            float t1 = Ssum[rl][0] + Ssum[rl][1] + Ssum[rl][2] + Ssum[rl][3];
            float t2 = Ssq[rl][0] + Ssq[rl][1] + Ssq[rl][2] + Ssq[rl][3];
            float mu = t1 * (1.0f / DD);
            float var = t2 * (1.0f / DD) - mu * mu;
            float rs = rsqrtf(var + 1e-5f);
            int row = row0 + rl;
            #pragma unroll
            for (int tj = 0; tj < 4; ++tj) {
                int colb = colw0 + tj * 16 + lo;
                Xn[(size_t)row * DD + colb] =
                    f2bfs((vv[ti][tj][r] - mu) * rs * ln1w[colb] + ln1b[colb]);
            }
        }
}

// ---------- MFMA retention (32 q-rows/wave) + groupnorm(32) + silu gate ----------
// r7-proven structure + V-TRANSPOSED input (see qkvg): staging code is byte-identical
// (tile internally permuted), but LDS now holds VT[d][t] -> the 16 scalar ds_read_u16
// V-fragment gathers become 4 contiguous ds_read_b64s (LDS-issue was the bottleneck:
// ~140 LDS cyc/chunk/wave x 16 waves/CU shared pipe ~ 32 us/layer).
#define VSTR 44
__global__ __launch_bounds__(256) void retention_mfma_kernel(bf16* __restrict__ QKVG,
                                                             const float* __restrict__ gnw,
                                                             const float* __restrict__ gnb) {
    __shared__ __align__(16) short Vt[4][32 * VSTR];
    const int wslot = threadIdx.x >> 6;
    const int lane = threadIdx.x & 63;
    const int gblk = blockIdx.x >> 6;                 // 0..15
    const int qi = 15 - ((gblk & ~3) + (((gblk & 3) + (gblk >> 2)) & 3));
    const int bh = ((blockIdx.x & 63) << 2) | wslot;
    const int b = bh >> 3, h = bh & 7;
    const int q0 = qi * 32;
    const int lo = lane & 15, quad = lane >> 4;

    const float la0 = -3.46573590280f, la1 = -6.23832462504f;
    float gamma = 1.0f - expf(la0 + (float)h * (la1 - la0) / 7.0f);
    float lg2 = log2f(gamma);
    float g16i = exp2f(-16.0f * lg2);                 // gamma^-16
    float g16p = exp2f(16.0f * lg2);                  // gamma^+16
    float gi32 = exp2f(-32.0f * lg2);                 // gamma^-32
    float wq[4], wq16[4], wqB[4];
    #pragma unroll
    for (int r = 0; r < 4; ++r) {
        wq[r]   = exp2f((float)(lo - 4 * quad - r) * lg2);
        wq16[r] = wq[r] * g16i;
        wqB[r]  = wq[r] * g16p;
    }
    float c = exp2f((float)q0 * lg2);                 // gamma^(q0 - t0), t0=0

    const size_t base = (size_t)b * SS * 1024;
    const short* QKVGs = (const short*)QKVG;

    short8 qfA = *(const short8*)(QKVGs + base + (size_t)(q0 + lo) * 1024 + h * HDIM + quad * 8);
    short8 qfB = *(const short8*)(QKVGs + base + (size_t)(q0 + 16 + lo) * 1024 + h * HDIM + quad * 8);

    floatx4 oA0 = {0,0,0,0}, oA1 = {0,0,0,0}, oB0 = {0,0,0,0}, oB1 = {0,0,0,0};
    short* Vw = Vt[wslot];
    const int nch = qi + 1;

    for (int ch = 0; ch < nch; ++ch) {
        const int t0 = ch * 32;
        const short* Kb = QKVGs + base + 256 + h * HDIM + quad * 8;
        short8 kf0 = *(const short8*)(Kb + (size_t)(t0 + lo) * 1024);
        short8 kf1 = *(const short8*)(Kb + (size_t)(t0 + 16 + lo) * 1024);
        {   // stage VT tile (addresses unchanged; content is V transposed-in-tile)
            // Vw[a*VSTR + b] = V[t0 + b][a]  (a = head-dim, b = t within chunk)
            const int r = lane >> 2, dcol = (lane & 3) * 8;
            const short* Vg = QKVGs + base + 512 + h * HDIM + dcol;
            uint4 u1 = *(const uint4*)(Vg + (size_t)(t0 + r) * 1024);
            uint4 u2 = *(const uint4*)(Vg + (size_t)(t0 + 16 + r) * 1024);
            uint_al* W1 = (uint_al*)(Vw + r * VSTR + dcol);
            uint_al* W2 = (uint_al*)(Vw + (16 + r) * VSTR + dcol);
            W1[0] = u1.x; W1[1] = u1.y; W1[2] = u1.z; W1[3] = u1.w;
            W2[0] = u2.x; W2[1] = u2.y; W2[2] = u2.z; W2[3] = u2.w;
        }
        const floatx4 z = {0,0,0,0};
        // swapped: lane holds S[q = lo (+16 for B)][t = t0 + 4*quad + r (+16 for *1)]
        __builtin_amdgcn_s_setprio(1);
        floatx4 sA0 = __builtin_amdgcn_mfma_f32_16x16x32_bf16(kf0, qfA, z, 0, 0, 0);
        floatx4 sA1 = __builtin_amdgcn_mfma_f32_16x16x32_bf16(kf1, qfA, z, 0, 0, 0);
        floatx4 sB0 = __builtin_amdgcn_mfma_f32_16x16x32_bf16(kf0, qfB, z, 0, 0, 0);
        floatx4 sB1 = __builtin_amdgcn_mfma_f32_16x16x32_bf16(kf1, qfB, z, 0, 0, 0);
        __builtin_amdgcn_s_setprio(0);

        float m0[4], m1[4], mB[4];
        #pragma unroll
        for (int r = 0; r < 4; ++r) {
            m0[r] = c * wq[r];        // sA0 and sB1 share exponent AND mask
            m1[r] = c * wq16[r];      // sA1
            mB[r] = c * wqB[r];       // sB0 (never masked)
        }
        if (ch == qi) {               // only the diagonal chunk has masked entries
            #pragma unroll
            for (int r = 0; r < 4; ++r) {
                if (lo < 4 * quad + r) m0[r] = 0.0f;
                m1[r] = 0.0f;         // sA1 fully masked on diagonal
            }
        }
        c *= gi32;

        unsigned int pa0 = cvtpk(sA0[0] * m0[0], sA0[1] * m0[1]);
        unsigned int pa1 = cvtpk(sA0[2] * m0[2], sA0[3] * m0[3]);
        unsigned int pa2 = cvtpk(sA1[0] * m1[0], sA1[1] * m1[1]);
        unsigned int pa3 = cvtpk(sA1[2] * m1[2], sA1[3] * m1[3]);
        unsigned int pb0 = cvtpk(sB0[0] * mB[0], sB0[1] * mB[1]);
        unsigned int pb1 = cvtpk(sB0[2] * mB[2], sB0[3] * mB[3]);
        unsigned int pb2 = cvtpk(sB1[0] * m0[0], sB1[1] * m0[1]);
        unsigned int pb3 = cvtpk(sB1[2] * m0[2], sB1[3] * m0[3]);
        short4v pA0 = mk4(pa0, pa1), pA1 = mk4(pa2, pa3);
        short4v pB0 = mk4(pb0, pb1), pB1 = mk4(pb2, pb3);

        // V fragments: contiguous b64 reads from VT layout (was 16 scalar u16 reads)
        const short* Vr0 = Vw + lo * VSTR;
        const short* Vr1 = Vw + (16 + lo) * VSTR;
        short4v v00 = *(const short4v*)(Vr0 + 4 * quad);
        short4v v01 = *(const short4v*)(Vr0 + 16 + 4 * quad);
        short4v v10 = *(const short4v*)(Vr1 + 4 * quad);
        short4v v11 = *(const short4v*)(Vr1 + 16 + 4 * quad);

        __builtin_amdgcn_s_setprio(1);
        oA0 = mfma16(pA0, v00, oA0);
        oA0 = mfma16(pA1, v01, oA0);
        oA1 = mfma16(pA0, v10, oA1);
        oA1 = mfma16(pA1, v11, oA1);
        oB0 = mfma16(pB0, v00, oB0);
        oB0 = mfma16(pB1, v01, oB0);
        oB1 = mfma16(pB0, v10, oB1);
        oB1 = mfma16(pB1, v11, oB1);
        __builtin_amdgcn_s_setprio(0);
    }

    float gw0 = gnw[h * HDIM + lo], gw1 = gnw[h * HDIM + 16 + lo];
    float gb0 = gnb[h * HDIM + lo], gb1 = gnb[h * HDIM + 16 + lo];
    bf16* QK = QKVG;
    #pragma unroll
    for (int sub = 0; sub < 2; ++sub) {
        floatx4 o0 = sub ? oB0 : oA0;
        floatx4 o1 = sub ? oB1 : oA1;
        int qbase = q0 + sub * 16;
        #pragma unroll
        for (int r = 0; r < 4; ++r) {
            float y0 = o0[r], y1 = o1[r];
            float s = y0 + y1, ss = y0 * y0 + y1 * y1;
            #pragma unroll
            for (int off = 1; off < 16; off <<= 1) {
                s  += __shfl_xor(s, off);
                ss += __shfl_xor(ss, off);
            }
            float mu = s * (1.0f / HDIM);
            float var = ss * (1.0f / HDIM) - mu * mu;
            float rstd = rsqrtf(var + 1e-5f);
            int q = qbase + quad * 4 + r;
            size_t rowb = base + (size_t)q * 1024;
            float g0 = bf2f(QK[rowb + 768 + h * HDIM + lo]);
            float g1 = bf2f(QK[rowb + 768 + h * HDIM + 16 + lo]);
            float t0v = g0 / (1.0f + expf(-g0)) * ((y0 - mu) * rstd * gw0 + gb0);
            float t1v = g1 / (1.0f + expf(-g1)) * ((y1 - mu) * rstd * gw1 + gb1);
            QK[rowb + h * HDIM + lo]      = f2bf(t0v);
            QK[rowb + h * HDIM + 16 + lo] = f2bf(t1v);
        }
    }
}

extern "C" void kernel_launch(void* const* d_in, const int* in_sizes, int n_in,
                              void* d_out, int out_size, void* d_ws, size_t ws_size,
                              hipStream_t stream) {
    const int*   v    = (const int*)d_in[0];
    const float* emb  = (const float*)d_in[1];
    const float* WQ   = (const float*)d_in[2];
    const float* WK   = (const float*)d_in[3];
    const float* WV   = (const float*)d_in[4];
    const float* WG   = (const float*)d_in[5];
    const float* WO   = (const float*)d_in[6];
    const float* gn_w = (const float*)d_in[7];
    const float* gn_b = (const float*)d_in[8];
    const float* ln1w = (const float*)d_in[9];
    const float* ln1b = (const float*)d_in[10];
    const float* ln2w = (const float*)d_in[11];
    const float* ln2b = (const float*)d_in[12];
    const float* w1   = (const float*)d_in[13];
    const float* b1   = (const float*)d_in[14];
    const float* w2   = (const float*)d_in[15];
    const float* b2   = (const float*)d_in[16];

    float* X = (float*)d_out;                    // residual stream (f32) in d_out

    float* base  = (float*)d_ws;
    int*   flag  = (int*)base;
    short* Xn    = (short*)(base + 16);          // NROWS*256 bf16
    bf16*  QKVG  = (bf16*)(Xn + (size_t)NROWS * 256);  // NROWS*1024
    bf16*  WqkvgP = QKVG + (size_t)NROWS * 1024; // 3*1024*256
    bf16*  WoP   = WqkvgP + 3 * 1024 * 256;      // 3*256*256
    bf16*  W1P   = WoP + 3 * 256 * 256;          // 3*128*256
    bf16*  W2P   = W1P + 3 * 128 * 256;          // 3*256*128
    float4* xpt  = (float4*)(W2P + 3 * 256 * 128); // 512*16 float4

    // setup_pack also zeroes flag (stream-ordered before detect_v's atomicOr)
    setup_pack<<<NSETUP / 256, 256, 0, stream>>>(WQ, WK, WV, WG, WO, w1, w2,
                                                 WqkvgP, WoP, W1P, W2P, xpt, flag);
    detect_v<<<32, 256, 0, stream>>>(v, flag);
    // X = relu(emb[v]); Xn = LN1_0(X); 8 rows/block
    embed_ln_kernel<<<NROWS / 8, 256, 0, stream>>>(v, emb, flag, ln1w, ln1b, X, Xn);

    for (int i = 0; i < 3; ++i) {
        // QKVG = xpos(Xn @ [WQ|WK|WV|WG]); V written transposed-in-tile
        qkvg_gemm<<<dim3(128, 8), 256, 0, stream>>>(Xn,
                                                    (const short*)(WqkvgP + (size_t)i * 1024 * 256),
                                                    xpt, QKVG);
        // retention + gn + gate (T into Q slot); 32-row q-tiles, 1024 blocks
        retention_mfma_kernel<<<1024, 256, 0, stream>>>(QKVG, gn_w + i * DD, gn_b + i * DD);
        // fused: Y = X + T@WO; Hn = LN2(Y); X = Y + gelu(Hn@w1+b1)@w2 + b2; LN1_next -> Xn
        if (i < 2)
            wo_ffn_fused<1><<<NROWS / 32, 256, 0, stream>>>((const short*)QKVG,
                                                            (const short*)(WoP + (size_t)i * 256 * 256),
                                                            (const short*)(W1P + (size_t)i * 128 * 256),
                                                            b1 + i * FFNN,
                                                            (const short*)(W2P + (size_t)i * 256 * 128),
                                                            b2 + i * DD, X,
                                                            ln2w + i * DD, ln2b + i * DD,
                                                            ln1w + (i + 1) * DD, ln1b + (i + 1) * DD, Xn);
        else
            wo_ffn_fused<0><<<NROWS / 32, 256, 0, stream>>>((const short*)QKVG,
                                                            (const short*)(WoP + (size_t)i * 256 * 256),
                                                            (const short*)(W1P + (size_t)i * 128 * 256),
                                                            b1 + i * FFNN,
                                                            (const short*)(W2P + (size_t)i * 256 * 128),
                                                            b2 + i * DD, X,
                                                            ln2w + i * DD, ln2b + i * DD,
                                                            nullptr, nullptr, nullptr);
    }
}

// Round 12
// 353.244 us; speedup vs baseline: 1.0109x; 1.0109x over previous
//
#include <hip/hip_runtime.h>
#include <hip/hip_bf16.h>
#include <math.h>

#define BB 32
#define SS 512
#define DD 256
#define HH 8
#define HDIM 32
#define FFNN 128
#define NROWS (BB*SS)        // 16384
#define NELEM (NROWS*DD)     // 4194304

using bf16 = __hip_bfloat16;
typedef __attribute__((ext_vector_type(8))) short short8;
typedef __attribute__((ext_vector_type(4))) short short4v;
typedef __attribute__((ext_vector_type(4))) float floatx4;
typedef unsigned int uint_al __attribute__((may_alias));

static __device__ __forceinline__ float bf2f(bf16 x) { return __bfloat162float(x); }
static __device__ __forceinline__ bf16  f2bf(float x) { return __float2bfloat16(x); }
static __device__ __forceinline__ short f2bfs(float x) {
    bf16 b = __float2bfloat16(x);
    return __builtin_bit_cast(short, b);
}

// pack two f32 -> one dword of two bf16 (no builtin on gfx950; RNE rounding)
static __device__ __forceinline__ unsigned int cvtpk(float a, float b) {
    unsigned int r;
    asm("v_cvt_pk_bf16_f32 %0, %1, %2" : "=v"(r) : "v"(a), "v"(b));
    return r;
}
static __device__ __forceinline__ short4v mk4(unsigned int a, unsigned int b) {
    union { unsigned int u[2]; short4v s; } t;
    t.u[0] = a; t.u[1] = b;
    return t.s;
}
static __device__ __forceinline__ floatx4 mfma16(short4v a, short4v b, floatx4 c) {
#if __has_builtin(__builtin_amdgcn_mfma_f32_16x16x16bf16_1k)
    return __builtin_amdgcn_mfma_f32_16x16x16bf16_1k(a, b, c, 0, 0, 0);
#else
    asm("v_mfma_f32_16x16x16_bf16 %0, %1, %2, %0" : "+v"(c) : "v"(a), "v"(b));
    return c;
#endif
}

// async global->LDS, 16B per lane; dest = wave-uniform base + lane*16
static __device__ __forceinline__ void gld_lds16(const void* g, void* l) {
    __builtin_amdgcn_global_load_lds(
        (const __attribute__((address_space(1))) void*)g,
        (__attribute__((address_space(3))) void*)l, 16, 0, 0);
}

// ---------- v dtype probe (flag zeroed by setup_pack, stream-ordered before this) ----------
__global__ __launch_bounds__(256) void detect_v(const int* __restrict__ v, int* __restrict__ flag) {
    int i = blockIdx.x * 256 + threadIdx.x;
    if (v[2 * i + 1] != 0) atomicOr(flag, 1);
}

// ---------- one-shot setup: all weight packs (f32 -> bf16 [n][k]) + xPos table + flag=0 ----------
#define NQKVG (3*1024*256)           // 786432
#define NWO   (3*256*256)            // 196608
#define NW1   (3*128*256)            // 98304
#define NW2   (3*256*128)            // 98304
#define NXPT  (512*16)               // 8192
#define NSETUP (NQKVG+NWO+NW1+NW2+NXPT)   // 1187840 = 4640*256
__global__ __launch_bounds__(256) void setup_pack(const float* __restrict__ WQ, const float* __restrict__ WK,
                                                  const float* __restrict__ WV, const float* __restrict__ WG,
                                                  const float* __restrict__ WO, const float* __restrict__ w1,
                                                  const float* __restrict__ w2,
                                                  bf16* __restrict__ dQ, bf16* __restrict__ dO,
                                                  bf16* __restrict__ d1, bf16* __restrict__ d2,
                                                  float4* __restrict__ xpt, int* __restrict__ flag) {
    int idx = blockIdx.x * 256 + threadIdx.x;
    if (idx == 0) *flag = 0;
    if (idx < NQKVG) {
        int k = idx & 255, n = (idx >> 8) & 1023, l = idx >> 18;
        int seg = n >> 8, n8 = n & 255;
        float val;
        if (seg < 3) {
            const float* W = (seg == 0) ? WQ : (seg == 1) ? WK : WV;
            int h = n8 >> 5, e = n8 & 31;
            val = W[(((size_t)l * 8 + h) * 256 + k) * 32 + e];
        } else {
            val = WG[(size_t)l * 65536 + k * 256 + n8];
        }
        dQ[((size_t)l * 1024 + n) * 256 + k] = f2bf(val);
    } else if (idx < NQKVG + NWO) {
        int i = idx - NQKVG;
        int k = i & 255, n = (i >> 8) & 255, l = i >> 16;
        dO[((size_t)l * 256 + n) * 256 + k] = f2bf(WO[(size_t)l * 65536 + k * 256 + n]);
    } else if (idx < NQKVG + NWO + NW1) {
        int i = idx - NQKVG - NWO;
        int k = i & 255, n = (i >> 8) & 127, l = i >> 15;
        d1[((size_t)l * 128 + n) * 256 + k] = f2bf(w1[(size_t)l * 32768 + k * 128 + n]);
    } else if (idx < NQKVG + NWO + NW1 + NW2) {
        int i = idx - NQKVG - NWO - NW1;
        int k = i & 127, n = (i >> 7) & 255, l = i >> 15;
        d2[((size_t)l * 256 + n) * 128 + k] = f2bf(w2[(size_t)l * 32768 + k * 256 + n]);
    } else {
        int i = idx - NQKVG - NWO - NW1 - NW2;     // 0..8191
        int jf = i & 15, s = i >> 4;
        float base = (2.0f * jf + 12.8f) / 44.8f;
        float sm = powf(base, (float)s * (1.0f / 512.0f));
        float ang = (float)s * powf(10000.0f, -(float)jf / 16.0f);
        float sn, cs;
        sincosf(ang, &sn, &cs);
        xpt[i] = float4{cs * sm, sn * sm, cs / sm, sn / sm};
    }
}

// ---------- fused embed + LN1(layer0): 8 rows per block (grid 2048) ----------
__global__ __launch_bounds__(256) void embed_ln_kernel(const int* __restrict__ v,
                                                       const float* __restrict__ emb,
                                                       const int* __restrict__ flag,
                                                       const float* __restrict__ w,
                                                       const float* __restrict__ b,
                                                       float* __restrict__ X,
                                                       short* __restrict__ Xn) {
    __shared__ float p1[4], p2[4], st[2];
    const int d = threadIdx.x;
    const int wid = threadIdx.x >> 6;
    const int is32 = *flag;
    const float wd = w[d], bd = b[d];
    for (int it = 0; it < 8; ++it) {
        int row = blockIdx.x * 8 + it;
        int tok = is32 ? v[row] : v[2 * row];
        float x = 0.0f;
        if (tok != 0) {
            x = emb[tok * DD + d];
            x = x > 0.0f ? x : 0.0f;
        }
        X[(size_t)row * DD + d] = x;
        float s1 = x, s2 = x * x;
        #pragma unroll
        for (int off = 1; off < 64; off <<= 1) {
            s1 += __shfl_xor(s1, off);
            s2 += __shfl_xor(s2, off);
        }
        if ((threadIdx.x & 63) == 0) { p1[wid] = s1; p2[wid] = s2; }
        __syncthreads();
        if (threadIdx.x == 0) {
            float t1 = p1[0] + p1[1] + p1[2] + p1[3];
            float t2 = p2[0] + p2[1] + p2[2] + p2[3];
            float mu = t1 * (1.0f / DD);
            float var = t2 * (1.0f / DD) - mu * mu;
            st[0] = mu; st[1] = rsqrtf(var + 1e-5f);
        }
        __syncthreads();
        Xn[(size_t)row * DD + d] = f2bfs((x - st[0]) * st[1] * wd + bd);
    }
}

// ---------- QKVG MFMA GEMM (128x128 tile; r10-proven, plain V layout) ----------
__global__ __launch_bounds__(256) void qkvg_gemm(const short* __restrict__ A,   // Xn, lda=256
                                                 const short* __restrict__ Bp,  // [1024][256] packed
                                                 const float4* __restrict__ xpt,
                                                 bf16* __restrict__ C) {        // ldc=1024
    __shared__ __align__(16) short Als[16 * 512];
    __shared__ __align__(16) short Bls[16 * 512];
    const int tid = threadIdx.x;
    const int wave = tid >> 6, lane = tid & 63, lo = lane & 15, quad = lane >> 4;
    const int wm = wave >> 1, wn = wave & 1;
    const int row0 = blockIdx.x * 128, col0 = blockIdx.y * 128;

    floatx4 acc[4][4];
    #pragma unroll
    for (int i = 0; i < 4; ++i)
        #pragma unroll
        for (int j = 0; j < 4; ++j) acc[i][j] = floatx4{0.f, 0.f, 0.f, 0.f};

    for (int k0 = 0; k0 < 256; k0 += 64) {
        #pragma unroll
        for (int t = 0; t < 4; ++t) {
            int grp = (wm * 4 + t) * 2 + wn;
            const short* ga = A + (size_t)(row0 + (wm * 4 + t) * 16 + lo) * 256
                            + k0 + (wn * 4 + quad) * 8;
            gld_lds16(ga, &Als[grp * 512]);
        }
        #pragma unroll
        for (int t = 0; t < 4; ++t) {
            int grp = (wn * 4 + t) * 2 + wm;
            const short* gb = Bp + (size_t)(col0 + (wn * 4 + t) * 16 + lo) * 256
                            + k0 + (wm * 4 + quad) * 8;
            gld_lds16(gb, &Bls[grp * 512]);
        }
        __syncthreads();
        #pragma unroll
        for (int kkgrp = 0; kkgrp < 2; ++kkgrp) {
            short8 af[4], bfr[4];
            #pragma unroll
            for (int t = 0; t < 4; ++t)
                af[t] = *(const short8*)(&Als[((wm * 4 + t) * 2 + kkgrp) * 512 + lane * 8]);
            #pragma unroll
            for (int t = 0; t < 4; ++t)
                bfr[t] = *(const short8*)(&Bls[((wn * 4 + t) * 2 + kkgrp) * 512 + lane * 8]);
            #pragma unroll
            for (int ti = 0; ti < 4; ++ti)
                #pragma unroll
                for (int tj = 0; tj < 4; ++tj)
                    acc[ti][tj] = __builtin_amdgcn_mfma_f32_16x16x32_bf16(af[ti], bfr[tj], acc[ti][tj], 0, 0, 0);
        }
        __syncthreads();
    }

    #pragma unroll
    for (int ti = 0; ti < 4; ++ti) {
        #pragma unroll
        for (int tj = 0; tj < 4; ++tj) {
            int colb = col0 + (wn * 4 + tj) * 16 + lo;
            int seg = colb >> 8;
            #pragma unroll
            for (int r = 0; r < 4; ++r) {
                int row = row0 + (wm * 4 + ti) * 16 + quad * 4 + r;
                float v = acc[ti][tj][r];
                if (seg < 2) {
                    int s = row & (SS - 1);
                    int jf = (colb & 31) >> 1;
                    float4 t = xpt[s * 16 + jf];
                    float cs = (seg == 0) ? t.x : t.z;
                    float sn = (seg == 0) ? t.y : t.w;
                    float p = __shfl_xor(v, 1);
                    v = (lo & 1) ? (v * cs + p * sn) : (v * cs - p * sn);
                }
                C[(size_t)row * 1024 + colb] = f2bf(v);
            }
        }
    }
}

// ---------- MEGA-FUSED v2: 512 threads, 8 waves = 8 heads (one head/wave).
// retention (r7-proven per-wave code, h = wave) -> T in LDS Tn; barrier;
// WO/FFN phases in r10-proven direct-load form (barrier-free k-loops).
// TLP: 512 blocks x 8 waves = 16 waves/CU (same as r7 retention). Balance:
// co-resident blocks (i, i+256) get qi and 15-qi (chunk sum 17). Cross-block
// overlap: low-qi blocks enter GEMM phases while siblings still do retention.
// Hn aliases Tn (all T reads precede the Ssum barrier that precedes Hn writes).
// LDS ~50 KB -> 2 blocks/CU. Saves T global write+read (33.6 MB/layer) + 1 launch.
#define TSTR 264   // T/Hn row stride (shorts)
#define HSTR 136   // Hf row stride (shorts)
#define VSTR 44
template<int DOLN>
__global__ __launch_bounds__(512) void ret_wo_ffn(const bf16* __restrict__ QKVG,
                                                  const float* __restrict__ gnw,
                                                  const float* __restrict__ gnb,
                                                  const short* __restrict__ Wo,    // [256][256]
                                                  const short* __restrict__ W1p,   // [128][256]
                                                  const float* __restrict__ b1,
                                                  const short* __restrict__ W2p,   // [256][128]
                                                  const float* __restrict__ b2,
                                                  float* __restrict__ X,
                                                  const float* __restrict__ ln2w,
                                                  const float* __restrict__ ln2b,
                                                  const float* __restrict__ ln1w,
                                                  const float* __restrict__ ln1b,
                                                  short* __restrict__ Xn) {
    __shared__ __align__(16) short Vt[8][32 * VSTR];  // 22.5 KB (wave-private)
    __shared__ __align__(16) short Tn[32 * TSTR];     // 16.9 KB: T, later Hn
    __shared__ __align__(16) short Hf[32 * HSTR];     // 8.7 KB
    __shared__ float Ssum[32][8], Ssq[32][8];         // 2 KB
    const int tid = threadIdx.x;
    const int wave = tid >> 6, lane = tid & 63, lo = lane & 15, quad = lane >> 4;
    const int blk = blockIdx.x;
    const int qi = (blk < 256) ? (blk & 15) : 15 - (blk & 15);
    const int bb = (blk & 255) >> 4 | ((blk >> 4) & 16);   // 0..15, +16 for 2nd half
    const int q0 = qi * 32;
    const int row0 = bb * SS + q0;
    const int h = wave;
    const int kq = quad * 8;

    // ================= retention (one head per wave; no barriers inside) =============
    const size_t base = (size_t)bb * SS * 1024;
    const short* QKVGs = (const short*)QKVG;
    const float la0 = -3.46573590280f, la1 = -6.23832462504f;
    float gamma = 1.0f - expf(la0 + (float)h * (la1 - la0) / 7.0f);
    float lg2 = log2f(gamma);
    float g16i = exp2f(-16.0f * lg2);
    float g16p = exp2f(16.0f * lg2);
    float gi32 = exp2f(-32.0f * lg2);
    float wq[4], wq16[4], wqB[4];
    #pragma unroll
    for (int r = 0; r < 4; ++r) {
        wq[r]   = exp2f((float)(lo - 4 * quad - r) * lg2);
        wq16[r] = wq[r] * g16i;
        wqB[r]  = wq[r] * g16p;
    }
    float c = exp2f((float)q0 * lg2);

    short8 qfA = *(const short8*)(QKVGs + base + (size_t)(q0 + lo) * 1024 + h * HDIM + kq);
    short8 qfB = *(const short8*)(QKVGs + base + (size_t)(q0 + 16 + lo) * 1024 + h * HDIM + kq);

    floatx4 oA0 = {0,0,0,0}, oA1 = {0,0,0,0}, oB0 = {0,0,0,0}, oB1 = {0,0,0,0};
    short* Vw = Vt[wave];
    const int nch = qi + 1;

    for (int ch = 0; ch < nch; ++ch) {
        const int t0 = ch * 32;
        const short* Kb = QKVGs + base + 256 + h * HDIM + kq;
        short8 kf0 = *(const short8*)(Kb + (size_t)(t0 + lo) * 1024);
        short8 kf1 = *(const short8*)(Kb + (size_t)(t0 + 16 + lo) * 1024);
        {   // stage V rows t0..t0+31 into Vw[t][d] (row-major, stride VSTR)
            const int vr = lane >> 2, dcol = (lane & 3) * 8;
            const short* Vg = QKVGs + base + 512 + h * HDIM + dcol;
            uint4 u1 = *(const uint4*)(Vg + (size_t)(t0 + vr) * 1024);
            uint4 u2 = *(const uint4*)(Vg + (size_t)(t0 + 16 + vr) * 1024);
            uint_al* W1 = (uint_al*)(Vw + vr * VSTR + dcol);
            uint_al* W2 = (uint_al*)(Vw + (16 + vr) * VSTR + dcol);
            W1[0] = u1.x; W1[1] = u1.y; W1[2] = u1.z; W1[3] = u1.w;
            W2[0] = u2.x; W2[1] = u2.y; W2[2] = u2.z; W2[3] = u2.w;
        }
        const floatx4 z = {0,0,0,0};
        // swapped: lane holds S[q = lo (+16 for B)][t = t0 + 4*quad + r (+16 for *1)]
        __builtin_amdgcn_s_setprio(1);
        floatx4 sA0 = __builtin_amdgcn_mfma_f32_16x16x32_bf16(kf0, qfA, z, 0, 0, 0);
        floatx4 sA1 = __builtin_amdgcn_mfma_f32_16x16x32_bf16(kf1, qfA, z, 0, 0, 0);
        floatx4 sB0 = __builtin_amdgcn_mfma_f32_16x16x32_bf16(kf0, qfB, z, 0, 0, 0);
        floatx4 sB1 = __builtin_amdgcn_mfma_f32_16x16x32_bf16(kf1, qfB, z, 0, 0, 0);
        __builtin_amdgcn_s_setprio(0);

        float m0[4], m1[4], mB[4];
        #pragma unroll
        for (int r = 0; r < 4; ++r) {
            m0[r] = c * wq[r];        // sA0 and sB1 share exponent AND mask
            m1[r] = c * wq16[r];      // sA1
            mB[r] = c * wqB[r];       // sB0 (never masked)
        }
        if (ch == qi) {
            #pragma unroll
            for (int r = 0; r < 4; ++r) {
                if (lo < 4 * quad + r) m0[r] = 0.0f;
                m1[r] = 0.0f;
            }
        }
        c *= gi32;

        unsigned int pa0 = cvtpk(sA0[0] * m0[0], sA0[1] * m0[1]);
        unsigned int pa1 = cvtpk(sA0[2] * m0[2], sA0[3] * m0[3]);
        unsigned int pa2 = cvtpk(sA1[0] * m1[0], sA1[1] * m1[1]);
        unsigned int pa3 = cvtpk(sA1[2] * m1[2], sA1[3] * m1[3]);
        unsigned int pb0 = cvtpk(sB0[0] * mB[0], sB0[1] * mB[1]);
        unsigned int pb1 = cvtpk(sB0[2] * mB[2], sB0[3] * mB[3]);
        unsigned int pb2 = cvtpk(sB1[0] * m0[0], sB1[1] * m0[1]);
        unsigned int pb3 = cvtpk(sB1[2] * m0[2], sB1[3] * m0[3]);
        short4v pA0 = mk4(pa0, pa1), pA1 = mk4(pa2, pa3);
        short4v pB0 = mk4(pb0, pb1), pB1 = mk4(pb2, pb3);

        short4v v00, v01, v10, v11;
        #pragma unroll
        for (int j = 0; j < 4; ++j) {
            v00[j] = Vw[(4 * quad + j) * VSTR + lo];
            v01[j] = Vw[(16 + 4 * quad + j) * VSTR + lo];
            v10[j] = Vw[(4 * quad + j) * VSTR + 16 + lo];
            v11[j] = Vw[(16 + 4 * quad + j) * VSTR + 16 + lo];
        }
        __builtin_amdgcn_s_setprio(1);
        oA0 = mfma16(pA0, v00, oA0);
        oA0 = mfma16(pA1, v01, oA0);
        oA1 = mfma16(pA0, v10, oA1);
        oA1 = mfma16(pA1, v11, oA1);
        oB0 = mfma16(pB0, v00, oB0);
        oB0 = mfma16(pB1, v01, oB0);
        oB1 = mfma16(pB0, v10, oB1);
        oB1 = mfma16(pB1, v11, oB1);
        __builtin_amdgcn_s_setprio(0);
    }

    // gn + silu gate -> T rows into Tn (LDS), this wave's cols h*32..h*32+31
    {
        float gw0 = gnw[h * HDIM + lo], gw1 = gnw[h * HDIM + 16 + lo];
        float gb0 = gnb[h * HDIM + lo], gb1 = gnb[h * HDIM + 16 + lo];
        #pragma unroll
        for (int sub = 0; sub < 2; ++sub) {
            floatx4 o0 = sub ? oB0 : oA0;
            floatx4 o1 = sub ? oB1 : oA1;
            #pragma unroll
            for (int r = 0; r < 4; ++r) {
                float y0 = o0[r], y1 = o1[r];
                float s = y0 + y1, ss = y0 * y0 + y1 * y1;
                #pragma unroll
                for (int off = 1; off < 16; off <<= 1) {
                    s  += __shfl_xor(s, off);
                    ss += __shfl_xor(ss, off);
                }
                float mu = s * (1.0f / HDIM);
                float var = ss * (1.0f / HDIM) - mu * mu;
                float rstd = rsqrtf(var + 1e-5f);
                int rl = sub * 16 + quad * 4 + r;
                size_t rowb = base + (size_t)(q0 + rl) * 1024;
                float g0 = bf2f(QKVG[rowb + 768 + h * HDIM + lo]);
                float g1 = bf2f(QKVG[rowb + 768 + h * HDIM + 16 + lo]);
                float t0v = g0 / (1.0f + expf(-g0)) * ((y0 - mu) * rstd * gw0 + gb0);
                float t1v = g1 / (1.0f + expf(-g1)) * ((y1 - mu) * rstd * gw1 + gb1);
                Tn[rl * TSTR + h * HDIM + lo]      = f2bfs(t0v);
                Tn[rl * TSTR + h * HDIM + 16 + lo] = f2bfs(t1v);
            }
        }
    }
    __syncthreads();   // T complete in LDS

    // ================= phase W: acc = T @ WO, K=256 (A from Tn, B direct) =============
    floatx4 acc[2][2];
    #pragma unroll
    for (int i = 0; i < 2; ++i) { acc[i][0] = floatx4{0,0,0,0}; acc[i][1] = floatx4{0,0,0,0}; }
    for (int k0 = 0; k0 < 256; k0 += 64) {
        #pragma unroll
        for (int kk = 0; kk < 2; ++kk) {
            const int kof = k0 + kk * 32 + kq;
            short8 af[2], bfr[2];
            #pragma unroll
            for (int t = 0; t < 2; ++t)
                af[t] = *(const short8*)(&Tn[(t * 16 + lo) * TSTR + kof]);
            #pragma unroll
            for (int t = 0; t < 2; ++t)
                bfr[t] = *(const short8*)(Wo + (size_t)(wave * 32 + t * 16 + lo) * 256 + kof);
            #pragma unroll
            for (int ti = 0; ti < 2; ++ti)
                #pragma unroll
                for (int tj = 0; tj < 2; ++tj)
                    acc[ti][tj] = __builtin_amdgcn_mfma_f32_16x16x32_bf16(af[ti], bfr[tj], acc[ti][tj], 0, 0, 0);
        }
    }

    // Y = X + acc (regs); LN2 partials
    float vv[2][2][4];
    #pragma unroll
    for (int ti = 0; ti < 2; ++ti)
        #pragma unroll
        for (int tj = 0; tj < 2; ++tj) {
            int colb = wave * 32 + tj * 16 + lo;
            #pragma unroll
            for (int r = 0; r < 4; ++r) {
                int row = row0 + ti * 16 + quad * 4 + r;
                vv[ti][tj][r] = acc[ti][tj][r] + X[(size_t)row * DD + colb];
            }
        }
    #pragma unroll
    for (int ti = 0; ti < 2; ++ti)
        #pragma unroll
        for (int r = 0; r < 4; ++r) {
            float s1 = 0.f, s2 = 0.f;
            #pragma unroll
            for (int tj = 0; tj < 2; ++tj) {
                float v = vv[ti][tj][r];
                s1 += v; s2 += v * v;
            }
            #pragma unroll
            for (int off = 1; off < 16; off <<= 1) {
                s1 += __shfl_xor(s1, off);
                s2 += __shfl_xor(s2, off);
            }
            if (lo == 0) {
                int rl = ti * 16 + quad * 4 + r;
                Ssum[rl][wave] = s1;
                Ssq[rl][wave] = s2;
            }
        }
    __syncthreads();   // all Tn reads done; Ssum ready -> safe to overwrite Tn with Hn
    #pragma unroll
    for (int ti = 0; ti < 2; ++ti)
        #pragma unroll
        for (int r = 0; r < 4; ++r) {
            int rl = ti * 16 + quad * 4 + r;
            float t1 = 0.f, t2 = 0.f;
            #pragma unroll
            for (int w8 = 0; w8 < 8; ++w8) { t1 += Ssum[rl][w8]; t2 += Ssq[rl][w8]; }
            float mu = t1 * (1.0f / DD);
            float var = t2 * (1.0f / DD) - mu * mu;
            float rs = rsqrtf(var + 1e-5f);
            #pragma unroll
            for (int tj = 0; tj < 2; ++tj) {
                int colb = wave * 32 + tj * 16 + lo;
                Tn[rl * TSTR + colb] =
                    f2bfs((vv[ti][tj][r] - mu) * rs * ln2w[colb] + ln2b[colb]);
            }
        }
    __syncthreads();   // Hn (in Tn) complete

    // ================= phase 1: a1 = Hn @ w1, K=256; wave owns 16 cols ================
    floatx4 a1[2];
    a1[0] = floatx4{0,0,0,0}; a1[1] = floatx4{0,0,0,0};
    for (int k0 = 0; k0 < 256; k0 += 64) {
        #pragma unroll
        for (int kk = 0; kk < 2; ++kk) {
            const int kof = k0 + kk * 32 + kq;
            short8 af[2], bfr;
            #pragma unroll
            for (int t = 0; t < 2; ++t)
                af[t] = *(const short8*)(&Tn[(t * 16 + lo) * TSTR + kof]);
            bfr = *(const short8*)(W1p + (size_t)(wave * 16 + lo) * 256 + kof);
            #pragma unroll
            for (int ti = 0; ti < 2; ++ti)
                a1[ti] = __builtin_amdgcn_mfma_f32_16x16x32_bf16(af[ti], bfr, a1[ti], 0, 0, 0);
        }
    }
    // gelu -> Hf (wave's 16 cols)
    {
        int colb = wave * 16 + lo;
        float bs = b1[colb];
        #pragma unroll
        for (int ti = 0; ti < 2; ++ti)
            #pragma unroll
            for (int r = 0; r < 4; ++r) {
                int rl = ti * 16 + quad * 4 + r;
                float v = a1[ti][r] + bs;
                v = 0.5f * v * (1.0f + erff(v * 0.70710678118f));
                Hf[rl * HSTR + colb] = f2bfs(v);
            }
    }
    __syncthreads();   // Hf complete

    // ================= phase 2: a2 = Hf @ w2, K=128; wave owns 32 cols ================
    floatx4 a2[2][2];
    #pragma unroll
    for (int i = 0; i < 2; ++i) { a2[i][0] = floatx4{0,0,0,0}; a2[i][1] = floatx4{0,0,0,0}; }
    for (int k0 = 0; k0 < 128; k0 += 64) {
        #pragma unroll
        for (int kk = 0; kk < 2; ++kk) {
            const int kof = k0 + kk * 32 + kq;
            short8 af[2], bfr[2];
            #pragma unroll
            for (int t = 0; t < 2; ++t)
                af[t] = *(const short8*)(&Hf[(t * 16 + lo) * HSTR + kof]);
            #pragma unroll
            for (int t = 0; t < 2; ++t)
                bfr[t] = *(const short8*)(W2p + (size_t)(wave * 32 + t * 16 + lo) * 128 + kof);
            #pragma unroll
            for (int ti = 0; ti < 2; ++ti)
                #pragma unroll
                for (int tj = 0; tj < 2; ++tj)
                    a2[ti][tj] = __builtin_amdgcn_mfma_f32_16x16x32_bf16(af[ti], bfr[tj], a2[ti][tj], 0, 0, 0);
        }
    }

    // ================= final: X = Y + FFN; opt LN1_next -> Xn =================
    #pragma unroll
    for (int ti = 0; ti < 2; ++ti)
        #pragma unroll
        for (int tj = 0; tj < 2; ++tj) {
            int colb = wave * 32 + tj * 16 + lo;
            float bs = b2[colb];
            #pragma unroll
            for (int r = 0; r < 4; ++r) {
                int row = row0 + ti * 16 + quad * 4 + r;
                float v = a2[ti][tj][r] + bs + vv[ti][tj][r];
                X[(size_t)row * DD + colb] = v;
                vv[ti][tj][r] = v;
            }
        }
    if (!DOLN) return;
    #pragma unroll
    for (int ti = 0; ti < 2; ++ti)
        #pragma unroll
        for (int r = 0; r < 4; ++r) {
            float s1 = 0.f, s2 = 0.f;
            #pragma unroll
            for (int tj = 0; tj < 2; ++tj) {
                float v = vv[ti][tj][r];
                s1 += v; s2 += v * v;
            }
            #pragma unroll
            for (int off = 1; off < 16; off <<= 1) {
                s1 += __shfl_xor(s1, off);
                s2 += __shfl_xor(s2, off);
            }
            if (lo == 0) {
                int rl = ti * 16 + quad * 4 + r;
                Ssum[rl][wave] = s1;
                Ssq[rl][wave] = s2;
            }
        }
    __syncthreads();
    #pragma unroll
    for (int ti = 0; ti < 2; ++ti)
        #pragma unroll
        for (int r = 0; r < 4; ++r) {
            int rl = ti * 16 + quad * 4 + r;
            float t1 = 0.f, t2 = 0.f;
            #pragma unroll
            for (int w8 = 0; w8 < 8; ++w8) { t1 += Ssum[rl][w8]; t2 += Ssq[rl][w8]; }
            float mu = t1 * (1.0f / DD);
            float var = t2 * (1.0f / DD) - mu * mu;
            float rs = rsqrtf(var + 1e-5f);
            int row = row0 + rl;
            #pragma unroll
            for (int tj = 0; tj < 2; ++tj) {
                int colb = wave * 32 + tj * 16 + lo;
                Xn[(size_t)row * DD + colb] =
                    f2bfs((vv[ti][tj][r] - mu) * rs * ln1w[colb] + ln1b[colb]);
            }
        }
}

extern "C" void kernel_launch(void* const* d_in, const int* in_sizes, int n_in,
                              void* d_out, int out_size, void* d_ws, size_t ws_size,
                              hipStream_t stream) {
    const int*   v    = (const int*)d_in[0];
    const float* emb  = (const float*)d_in[1];
    const float* WQ   = (const float*)d_in[2];
    const float* WK   = (const float*)d_in[3];
    const float* WV   = (const float*)d_in[4];
    const float* WG   = (const float*)d_in[5];
    const float* WO   = (const float*)d_in[6];
    const float* gn_w = (const float*)d_in[7];
    const float* gn_b = (const float*)d_in[8];
    const float* ln1w = (const float*)d_in[9];
    const float* ln1b = (const float*)d_in[10];
    const float* ln2w = (const float*)d_in[11];
    const float* ln2b = (const float*)d_in[12];
    const float* w1   = (const float*)d_in[13];
    const float* b1   = (const float*)d_in[14];
    const float* w2   = (const float*)d_in[15];
    const float* b2   = (const float*)d_in[16];

    float* X = (float*)d_out;                    // residual stream (f32) in d_out

    float* base  = (float*)d_ws;
    int*   flag  = (int*)base;
    short* Xn    = (short*)(base + 16);          // NROWS*256 bf16
    bf16*  QKVG  = (bf16*)(Xn + (size_t)NROWS * 256);  // NROWS*1024
    bf16*  WqkvgP = QKVG + (size_t)NROWS * 1024; // 3*1024*256
    bf16*  WoP   = WqkvgP + 3 * 1024 * 256;      // 3*256*256
    bf16*  W1P   = WoP + 3 * 256 * 256;          // 3*128*256
    bf16*  W2P   = W1P + 3 * 128 * 256;          // 3*256*128
    float4* xpt  = (float4*)(W2P + 3 * 256 * 128); // 512*16 float4

    // setup_pack also zeroes flag (stream-ordered before detect_v's atomicOr)
    setup_pack<<<NSETUP / 256, 256, 0, stream>>>(WQ, WK, WV, WG, WO, w1, w2,
                                                 WqkvgP, WoP, W1P, W2P, xpt, flag);
    detect_v<<<32, 256, 0, stream>>>(v, flag);
    // X = relu(emb[v]); Xn = LN1_0(X); 8 rows/block
    embed_ln_kernel<<<NROWS / 8, 256, 0, stream>>>(v, emb, flag, ln1w, ln1b, X, Xn);

    for (int i = 0; i < 3; ++i) {
        // QKVG = xpos(Xn @ [WQ|WK|WV|WG])
        qkvg_gemm<<<dim3(128, 8), 256, 0, stream>>>(Xn,
                                                    (const short*)(WqkvgP + (size_t)i * 1024 * 256),
                                                    xpt, QKVG);
        // mega-fused: retention(8 heads, 1/wave) -> T in LDS -> WO -> LN2 -> FFN -> X, Xn
        if (i < 2)
            ret_wo_ffn<1><<<512, 512, 0, stream>>>(QKVG, gn_w + i * DD, gn_b + i * DD,
                                                   (const short*)(WoP + (size_t)i * 256 * 256),
                                                   (const short*)(W1P + (size_t)i * 128 * 256),
                                                   b1 + i * FFNN,
                                                   (const short*)(W2P + (size_t)i * 256 * 128),
                                                   b2 + i * DD, X,
                                                   ln2w + i * DD, ln2b + i * DD,
                                                   ln1w + (i + 1) * DD, ln1b + (i + 1) * DD, Xn);
        else
            ret_wo_ffn<0><<<512, 512, 0, stream>>>(QKVG, gn_w + i * DD, gn_b + i * DD,
                                                   (const short*)(WoP + (size_t)i * 256 * 256),
                                                   (const short*)(W1P + (size_t)i * 128 * 256),
                                                   b1 + i * FFNN,
                                                   (const short*)(W2P + (size_t)i * 256 * 128),
                                                   b2 + i * DD, X,
                                                   ln2w + i * DD, ln2b + i * DD,
                                                   nullptr, nullptr, nullptr);
    }
}

// Round 13
// 346.918 us; speedup vs baseline: 1.0293x; 1.0182x over previous
//
#include <hip/hip_runtime.h>
#include <hip/hip_bf16.h>
#include <math.h>

#define BB 32
#define SS 512
#define DD 256
#define HH 8
#define HDIM 32
#define FFNN 128
#define NROWS (BB*SS)        // 16384
#define NELEM (NROWS*DD)     // 4194304

using bf16 = __hip_bfloat16;
typedef __attribute__((ext_vector_type(8))) short short8;
typedef __attribute__((ext_vector_type(4))) short short4v;
typedef __attribute__((ext_vector_type(4))) float floatx4;
typedef unsigned int uint_al __attribute__((may_alias));

static __device__ __forceinline__ float bf2f(bf16 x) { return __bfloat162float(x); }
static __device__ __forceinline__ bf16  f2bf(float x) { return __float2bfloat16(x); }
static __device__ __forceinline__ short f2bfs(float x) {
    bf16 b = __float2bfloat16(x);
    return __builtin_bit_cast(short, b);
}

// pack two f32 -> one dword of two bf16 (no builtin on gfx950; RNE rounding)
static __device__ __forceinline__ unsigned int cvtpk(float a, float b) {
    unsigned int r;
    asm("v_cvt_pk_bf16_f32 %0, %1, %2" : "=v"(r) : "v"(a), "v"(b));
    return r;
}
static __device__ __forceinline__ short4v mk4(unsigned int a, unsigned int b) {
    union { unsigned int u[2]; short4v s; } t;
    t.u[0] = a; t.u[1] = b;
    return t.s;
}
static __device__ __forceinline__ floatx4 mfma16(short4v a, short4v b, floatx4 c) {
#if __has_builtin(__builtin_amdgcn_mfma_f32_16x16x16bf16_1k)
    return __builtin_amdgcn_mfma_f32_16x16x16bf16_1k(a, b, c, 0, 0, 0);
#else
    asm("v_mfma_f32_16x16x16_bf16 %0, %1, %2, %0" : "+v"(c) : "v"(a), "v"(b));
    return c;
#endif
}

// async global->LDS, 16B per lane; dest = wave-uniform base + lane*16
static __device__ __forceinline__ void gld_lds16(const void* g, void* l) {
    __builtin_amdgcn_global_load_lds(
        (const __attribute__((address_space(1))) void*)g,
        (__attribute__((address_space(3))) void*)l, 16, 0, 0);
}

// ---------- v dtype probe (flag zeroed by setup_pack, stream-ordered before this) ----------
__global__ __launch_bounds__(256) void detect_v(const int* __restrict__ v, int* __restrict__ flag) {
    int i = blockIdx.x * 256 + threadIdx.x;
    if (v[2 * i + 1] != 0) atomicOr(flag, 1);
}

// ---------- one-shot setup: all weight packs (f32 -> bf16 [n][k]) + xPos table + flag=0 ----------
#define NQKVG (3*1024*256)           // 786432
#define NWO   (3*256*256)            // 196608
#define NW1   (3*128*256)            // 98304
#define NW2   (3*256*128)            // 98304
#define NXPT  (512*16)               // 8192
#define NSETUP (NQKVG+NWO+NW1+NW2+NXPT)   // 1187840 = 4640*256
__global__ __launch_bounds__(256) void setup_pack(const float* __restrict__ WQ, const float* __restrict__ WK,
                                                  const float* __restrict__ WV, const float* __restrict__ WG,
                                                  const float* __restrict__ WO, const float* __restrict__ w1,
                                                  const float* __restrict__ w2,
                                                  bf16* __restrict__ dQ, bf16* __restrict__ dO,
                                                  bf16* __restrict__ d1, bf16* __restrict__ d2,
                                                  float4* __restrict__ xpt, int* __restrict__ flag) {
    int idx = blockIdx.x * 256 + threadIdx.x;
    if (idx == 0) *flag = 0;
    if (idx < NQKVG) {
        int k = idx & 255, n = (idx >> 8) & 1023, l = idx >> 18;
        int seg = n >> 8, n8 = n & 255;
        float val;
        if (seg < 3) {
            const float* W = (seg == 0) ? WQ : (seg == 1) ? WK : WV;
            int h = n8 >> 5, e = n8 & 31;
            val = W[(((size_t)l * 8 + h) * 256 + k) * 32 + e];
        } else {
            val = WG[(size_t)l * 65536 + k * 256 + n8];
        }
        dQ[((size_t)l * 1024 + n) * 256 + k] = f2bf(val);
    } else if (idx < NQKVG + NWO) {
        int i = idx - NQKVG;
        int k = i & 255, n = (i >> 8) & 255, l = i >> 16;
        dO[((size_t)l * 256 + n) * 256 + k] = f2bf(WO[(size_t)l * 65536 + k * 256 + n]);
    } else if (idx < NQKVG + NWO + NW1) {
        int i = idx - NQKVG - NWO;
        int k = i & 255, n = (i >> 8) & 127, l = i >> 15;
        d1[((size_t)l * 128 + n) * 256 + k] = f2bf(w1[(size_t)l * 32768 + k * 128 + n]);
    } else if (idx < NQKVG + NWO + NW1 + NW2) {
        int i = idx - NQKVG - NWO - NW1;
        int k = i & 127, n = (i >> 7) & 255, l = i >> 15;
        d2[((size_t)l * 256 + n) * 128 + k] = f2bf(w2[(size_t)l * 32768 + k * 256 + n]);
    } else {
        int i = idx - NQKVG - NWO - NW1 - NW2;     // 0..8191
        int jf = i & 15, s = i >> 4;
        float base = (2.0f * jf + 12.8f) / 44.8f;
        float sm = powf(base, (float)s * (1.0f / 512.0f));
        float ang = (float)s * powf(10000.0f, -(float)jf / 16.0f);
        float sn, cs;
        sincosf(ang, &sn, &cs);
        xpt[i] = float4{cs * sm, sn * sm, cs / sm, sn / sm};
    }
}

// ---------- fused embed + LN1(layer0): 8 rows per block (grid 2048) ----------
__global__ __launch_bounds__(256) void embed_ln_kernel(const int* __restrict__ v,
                                                       const float* __restrict__ emb,
                                                       const int* __restrict__ flag,
                                                       const float* __restrict__ w,
                                                       const float* __restrict__ b,
                                                       float* __restrict__ X,
                                                       short* __restrict__ Xn) {
    __shared__ float p1[4], p2[4], st[2];
    const int d = threadIdx.x;
    const int wid = threadIdx.x >> 6;
    const int is32 = *flag;
    const float wd = w[d], bd = b[d];
    for (int it = 0; it < 8; ++it) {
        int row = blockIdx.x * 8 + it;
        int tok = is32 ? v[row] : v[2 * row];
        float x = 0.0f;
        if (tok != 0) {
            x = emb[tok * DD + d];
            x = x > 0.0f ? x : 0.0f;
        }
        X[(size_t)row * DD + d] = x;
        float s1 = x, s2 = x * x;
        #pragma unroll
        for (int off = 1; off < 64; off <<= 1) {
            s1 += __shfl_xor(s1, off);
            s2 += __shfl_xor(s2, off);
        }
        if ((threadIdx.x & 63) == 0) { p1[wid] = s1; p2[wid] = s2; }
        __syncthreads();
        if (threadIdx.x == 0) {
            float t1 = p1[0] + p1[1] + p1[2] + p1[3];
            float t2 = p2[0] + p2[1] + p2[2] + p2[3];
            float mu = t1 * (1.0f / DD);
            float var = t2 * (1.0f / DD) - mu * mu;
            st[0] = mu; st[1] = rsqrtf(var + 1e-5f);
        }
        __syncthreads();
        Xn[(size_t)row * DD + d] = f2bfs((x - st[0]) * st[1] * wd + bd);
    }
}

// ---------- QKVG MFMA GEMM (128x128 tile) ----------
__global__ __launch_bounds__(256) void qkvg_gemm(const short* __restrict__ A,   // Xn, lda=256
                                                 const short* __restrict__ Bp,  // [1024][256] packed
                                                 const float4* __restrict__ xpt,
                                                 bf16* __restrict__ C) {        // ldc=1024
    __shared__ __align__(16) short Als[16 * 512];
    __shared__ __align__(16) short Bls[16 * 512];
    const int tid = threadIdx.x;
    const int wave = tid >> 6, lane = tid & 63, lo = lane & 15, quad = lane >> 4;
    const int wm = wave >> 1, wn = wave & 1;
    const int row0 = blockIdx.x * 128, col0 = blockIdx.y * 128;

    floatx4 acc[4][4];
    #pragma unroll
    for (int i = 0; i < 4; ++i)
        #pragma unroll
        for (int j = 0; j < 4; ++j) acc[i][j] = floatx4{0.f, 0.f, 0.f, 0.f};

    for (int k0 = 0; k0 < 256; k0 += 64) {
        #pragma unroll
        for (int t = 0; t < 4; ++t) {
            int grp = (wm * 4 + t) * 2 + wn;
            const short* ga = A + (size_t)(row0 + (wm * 4 + t) * 16 + lo) * 256
                            + k0 + (wn * 4 + quad) * 8;
            gld_lds16(ga, &Als[grp * 512]);
        }
        #pragma unroll
        for (int t = 0; t < 4; ++t) {
            int grp = (wn * 4 + t) * 2 + wm;
            const short* gb = Bp + (size_t)(col0 + (wn * 4 + t) * 16 + lo) * 256
                            + k0 + (wm * 4 + quad) * 8;
            gld_lds16(gb, &Bls[grp * 512]);
        }
        __syncthreads();
        #pragma unroll
        for (int kkgrp = 0; kkgrp < 2; ++kkgrp) {
            short8 af[4], bfr[4];
            #pragma unroll
            for (int t = 0; t < 4; ++t)
                af[t] = *(const short8*)(&Als[((wm * 4 + t) * 2 + kkgrp) * 512 + lane * 8]);
            #pragma unroll
            for (int t = 0; t < 4; ++t)
                bfr[t] = *(const short8*)(&Bls[((wn * 4 + t) * 2 + kkgrp) * 512 + lane * 8]);
            #pragma unroll
            for (int ti = 0; ti < 4; ++ti)
                #pragma unroll
                for (int tj = 0; tj < 4; ++tj)
                    acc[ti][tj] = __builtin_amdgcn_mfma_f32_16x16x32_bf16(af[ti], bfr[tj], acc[ti][tj], 0, 0, 0);
        }
        __syncthreads();
    }

    #pragma unroll
    for (int ti = 0; ti < 4; ++ti) {
        #pragma unroll
        for (int tj = 0; tj < 4; ++tj) {
            int colb = col0 + (wn * 4 + tj) * 16 + lo;
            int seg = colb >> 8;
            #pragma unroll
            for (int r = 0; r < 4; ++r) {
                int row = row0 + (wm * 4 + ti) * 16 + quad * 4 + r;
                float v = acc[ti][tj][r];
                if (seg < 2) {
                    int s = row & (SS - 1);
                    int jf = (colb & 31) >> 1;
                    float4 t = xpt[s * 16 + jf];
                    float cs = (seg == 0) ? t.x : t.z;
                    float sn = (seg == 0) ? t.y : t.w;
                    float p = __shfl_xor(v, 1);
                    v = (lo & 1) ? (v * cs + p * sn) : (v * cs - p * sn);
                }
                C[(size_t)row * 1024 + colb] = f2bf(v);
            }
        }
    }
}

// ---------- MEGA-FUSED v3: v2 + XCD-aware block map + VSTR 42 ----------
// r12 counters: 54us/layer, FETCH 84MB (unique ~52MB), hbm 26%, conflicts 1.47M ->
// memory-latency bound on redundant K/V fetch (qi-blocks of one batch spread over
// all 8 XCD L2s) + 4-way bank conflicts on V-staging writes (VSTR=44: 22-dword even
// stride -> 16 even banks only).
// Fix 1 (T1): xcd = blk&7 (dispatch round-robin), slot = blk>>3; all 16 qi-blocks of a
// batch land on ONE XCD (4 batches/XCD = 4MB ~ L2 size). Bijective; co-resident pair
// (blk, blk+256) keeps qi + (15-qi) -> nch sum 17 (balanced).
// Fix 2: VSTR 44 -> 42 (21 dwords, odd) -> staging-write banks cover all 32 (~2-way,
// free per m136); fragment reads stay conflict-free.
#define TSTR 264   // T/Hn row stride (shorts)
#define HSTR 136   // Hf row stride (shorts)
#define VSTR 42
template<int DOLN>
__global__ __launch_bounds__(512) void ret_wo_ffn(const bf16* __restrict__ QKVG,
                                                  const float* __restrict__ gnw,
                                                  const float* __restrict__ gnb,
                                                  const short* __restrict__ Wo,    // [256][256]
                                                  const short* __restrict__ W1p,   // [128][256]
                                                  const float* __restrict__ b1,
                                                  const short* __restrict__ W2p,   // [256][128]
                                                  const float* __restrict__ b2,
                                                  float* __restrict__ X,
                                                  const float* __restrict__ ln2w,
                                                  const float* __restrict__ ln2b,
                                                  const float* __restrict__ ln1w,
                                                  const float* __restrict__ ln1b,
                                                  short* __restrict__ Xn) {
    __shared__ __align__(16) short Vt[8][32 * VSTR];  // 21 KB (wave-private)
    __shared__ __align__(16) short Tn[32 * TSTR];     // 16.9 KB: T, later Hn
    __shared__ __align__(16) short Hf[32 * HSTR];     // 8.7 KB
    __shared__ float Ssum[32][8], Ssq[32][8];         // 2 KB
    const int tid = threadIdx.x;
    const int wave = tid >> 6, lane = tid & 63, lo = lane & 15, quad = lane >> 4;
    const int blk = blockIdx.x;
    // XCD-aware map: all 16 qi of a batch on one XCD; co-resident qi sums = 15
    const int xcd = blk & 7;
    const int slot = blk >> 3;                        // 0..63
    int qi, bbl;
    if (slot < 32) { qi = slot & 15; bbl = slot >> 4; }
    else { qi = 15 - (slot & 15); bbl = 2 + ((slot - 32) >> 4); }
    const int bb = (xcd << 2) | bbl;
    const int q0 = qi * 32;
    const int row0 = bb * SS + q0;
    const int h = wave;
    const int kq = quad * 8;

    // ================= retention (one head per wave; no barriers inside) =============
    const size_t base = (size_t)bb * SS * 1024;
    const short* QKVGs = (const short*)QKVG;
    const float la0 = -3.46573590280f, la1 = -6.23832462504f;
    float gamma = 1.0f - expf(la0 + (float)h * (la1 - la0) / 7.0f);
    float lg2 = log2f(gamma);
    float g16i = exp2f(-16.0f * lg2);
    float g16p = exp2f(16.0f * lg2);
    float gi32 = exp2f(-32.0f * lg2);
    float wq[4], wq16[4], wqB[4];
    #pragma unroll
    for (int r = 0; r < 4; ++r) {
        wq[r]   = exp2f((float)(lo - 4 * quad - r) * lg2);
        wq16[r] = wq[r] * g16i;
        wqB[r]  = wq[r] * g16p;
    }
    float c = exp2f((float)q0 * lg2);

    short8 qfA = *(const short8*)(QKVGs + base + (size_t)(q0 + lo) * 1024 + h * HDIM + kq);
    short8 qfB = *(const short8*)(QKVGs + base + (size_t)(q0 + 16 + lo) * 1024 + h * HDIM + kq);

    floatx4 oA0 = {0,0,0,0}, oA1 = {0,0,0,0}, oB0 = {0,0,0,0}, oB1 = {0,0,0,0};
    short* Vw = Vt[wave];
    const int nch = qi + 1;

    for (int ch = 0; ch < nch; ++ch) {
        const int t0 = ch * 32;
        const short* Kb = QKVGs + base + 256 + h * HDIM + kq;
        short8 kf0 = *(const short8*)(Kb + (size_t)(t0 + lo) * 1024);
        short8 kf1 = *(const short8*)(Kb + (size_t)(t0 + 16 + lo) * 1024);
        {   // stage V rows t0..t0+31 into Vw[t][d] (row-major, stride VSTR)
            const int vr = lane >> 2, dcol = (lane & 3) * 8;
            const short* Vg = QKVGs + base + 512 + h * HDIM + dcol;
            uint4 u1 = *(const uint4*)(Vg + (size_t)(t0 + vr) * 1024);
            uint4 u2 = *(const uint4*)(Vg + (size_t)(t0 + 16 + vr) * 1024);
            uint_al* W1 = (uint_al*)(Vw + vr * VSTR + dcol);
            uint_al* W2 = (uint_al*)(Vw + (16 + vr) * VSTR + dcol);
            W1[0] = u1.x; W1[1] = u1.y; W1[2] = u1.z; W1[3] = u1.w;
            W2[0] = u2.x; W2[1] = u2.y; W2[2] = u2.z; W2[3] = u2.w;
        }
        const floatx4 z = {0,0,0,0};
        // swapped: lane holds S[q = lo (+16 for B)][t = t0 + 4*quad + r (+16 for *1)]
        __builtin_amdgcn_s_setprio(1);
        floatx4 sA0 = __builtin_amdgcn_mfma_f32_16x16x32_bf16(kf0, qfA, z, 0, 0, 0);
        floatx4 sA1 = __builtin_amdgcn_mfma_f32_16x16x32_bf16(kf1, qfA, z, 0, 0, 0);
        floatx4 sB0 = __builtin_amdgcn_mfma_f32_16x16x32_bf16(kf0, qfB, z, 0, 0, 0);
        floatx4 sB1 = __builtin_amdgcn_mfma_f32_16x16x32_bf16(kf1, qfB, z, 0, 0, 0);
        __builtin_amdgcn_s_setprio(0);

        float m0[4], m1[4], mB[4];
        #pragma unroll
        for (int r = 0; r < 4; ++r) {
            m0[r] = c * wq[r];        // sA0 and sB1 share exponent AND mask
            m1[r] = c * wq16[r];      // sA1
            mB[r] = c * wqB[r];       // sB0 (never masked)
        }
        if (ch == qi) {
            #pragma unroll
            for (int r = 0; r < 4; ++r) {
                if (lo < 4 * quad + r) m0[r] = 0.0f;
                m1[r] = 0.0f;
            }
        }
        c *= gi32;

        unsigned int pa0 = cvtpk(sA0[0] * m0[0], sA0[1] * m0[1]);
        unsigned int pa1 = cvtpk(sA0[2] * m0[2], sA0[3] * m0[3]);
        unsigned int pa2 = cvtpk(sA1[0] * m1[0], sA1[1] * m1[1]);
        unsigned int pa3 = cvtpk(sA1[2] * m1[2], sA1[3] * m1[3]);
        unsigned int pb0 = cvtpk(sB0[0] * mB[0], sB0[1] * mB[1]);
        unsigned int pb1 = cvtpk(sB0[2] * mB[2], sB0[3] * mB[3]);
        unsigned int pb2 = cvtpk(sB1[0] * m0[0], sB1[1] * m0[1]);
        unsigned int pb3 = cvtpk(sB1[2] * m0[2], sB1[3] * m0[3]);
        short4v pA0 = mk4(pa0, pa1), pA1 = mk4(pa2, pa3);
        short4v pB0 = mk4(pb0, pb1), pB1 = mk4(pb2, pb3);

        short4v v00, v01, v10, v11;
        #pragma unroll
        for (int j = 0; j < 4; ++j) {
            v00[j] = Vw[(4 * quad + j) * VSTR + lo];
            v01[j] = Vw[(16 + 4 * quad + j) * VSTR + lo];
            v10[j] = Vw[(4 * quad + j) * VSTR + 16 + lo];
            v11[j] = Vw[(16 + 4 * quad + j) * VSTR + 16 + lo];
        }
        __builtin_amdgcn_s_setprio(1);
        oA0 = mfma16(pA0, v00, oA0);
        oA0 = mfma16(pA1, v01, oA0);
        oA1 = mfma16(pA0, v10, oA1);
        oA1 = mfma16(pA1, v11, oA1);
        oB0 = mfma16(pB0, v00, oB0);
        oB0 = mfma16(pB1, v01, oB0);
        oB1 = mfma16(pB0, v10, oB1);
        oB1 = mfma16(pB1, v11, oB1);
        __builtin_amdgcn_s_setprio(0);
    }

    // gn + silu gate -> T rows into Tn (LDS), this wave's cols h*32..h*32+31
    {
        float gw0 = gnw[h * HDIM + lo], gw1 = gnw[h * HDIM + 16 + lo];
        float gb0 = gnb[h * HDIM + lo], gb1 = gnb[h * HDIM + 16 + lo];
        #pragma unroll
        for (int sub = 0; sub < 2; ++sub) {
            floatx4 o0 = sub ? oB0 : oA0;
            floatx4 o1 = sub ? oB1 : oA1;
            #pragma unroll
            for (int r = 0; r < 4; ++r) {
                float y0 = o0[r], y1 = o1[r];
                float s = y0 + y1, ss = y0 * y0 + y1 * y1;
                #pragma unroll
                for (int off = 1; off < 16; off <<= 1) {
                    s  += __shfl_xor(s, off);
                    ss += __shfl_xor(ss, off);
                }
                float mu = s * (1.0f / HDIM);
                float var = ss * (1.0f / HDIM) - mu * mu;
                float rstd = rsqrtf(var + 1e-5f);
                int rl = sub * 16 + quad * 4 + r;
                size_t rowb = base + (size_t)(q0 + rl) * 1024;
                float g0 = bf2f(QKVG[rowb + 768 + h * HDIM + lo]);
                float g1 = bf2f(QKVG[rowb + 768 + h * HDIM + 16 + lo]);
                float t0v = g0 / (1.0f + expf(-g0)) * ((y0 - mu) * rstd * gw0 + gb0);
                float t1v = g1 / (1.0f + expf(-g1)) * ((y1 - mu) * rstd * gw1 + gb1);
                Tn[rl * TSTR + h * HDIM + lo]      = f2bfs(t0v);
                Tn[rl * TSTR + h * HDIM + 16 + lo] = f2bfs(t1v);
            }
        }
    }
    __syncthreads();   // T complete in LDS

    // ================= phase W: acc = T @ WO, K=256 (A from Tn, B direct) =============
    floatx4 acc[2][2];
    #pragma unroll
    for (int i = 0; i < 2; ++i) { acc[i][0] = floatx4{0,0,0,0}; acc[i][1] = floatx4{0,0,0,0}; }
    for (int k0 = 0; k0 < 256; k0 += 64) {
        #pragma unroll
        for (int kk = 0; kk < 2; ++kk) {
            const int kof = k0 + kk * 32 + kq;
            short8 af[2], bfr[2];
            #pragma unroll
            for (int t = 0; t < 2; ++t)
                af[t] = *(const short8*)(&Tn[(t * 16 + lo) * TSTR + kof]);
            #pragma unroll
            for (int t = 0; t < 2; ++t)
                bfr[t] = *(const short8*)(Wo + (size_t)(wave * 32 + t * 16 + lo) * 256 + kof);
            #pragma unroll
            for (int ti = 0; ti < 2; ++ti)
                #pragma unroll
                for (int tj = 0; tj < 2; ++tj)
                    acc[ti][tj] = __builtin_amdgcn_mfma_f32_16x16x32_bf16(af[ti], bfr[tj], acc[ti][tj], 0, 0, 0);
        }
    }

    // Y = X + acc (regs); LN2 partials
    float vv[2][2][4];
    #pragma unroll
    for (int ti = 0; ti < 2; ++ti)
        #pragma unroll
        for (int tj = 0; tj < 2; ++tj) {
            int colb = wave * 32 + tj * 16 + lo;
            #pragma unroll
            for (int r = 0; r < 4; ++r) {
                int row = row0 + ti * 16 + quad * 4 + r;
                vv[ti][tj][r] = acc[ti][tj][r] + X[(size_t)row * DD + colb];
            }
        }
    #pragma unroll
    for (int ti = 0; ti < 2; ++ti)
        #pragma unroll
        for (int r = 0; r < 4; ++r) {
            float s1 = 0.f, s2 = 0.f;
            #pragma unroll
            for (int tj = 0; tj < 2; ++tj) {
                float v = vv[ti][tj][r];
                s1 += v; s2 += v * v;
            }
            #pragma unroll
            for (int off = 1; off < 16; off <<= 1) {
                s1 += __shfl_xor(s1, off);
                s2 += __shfl_xor(s2, off);
            }
            if (lo == 0) {
                int rl = ti * 16 + quad * 4 + r;
                Ssum[rl][wave] = s1;
                Ssq[rl][wave] = s2;
            }
        }
    __syncthreads();   // all Tn reads done; Ssum ready -> safe to overwrite Tn with Hn
    #pragma unroll
    for (int ti = 0; ti < 2; ++ti)
        #pragma unroll
        for (int r = 0; r < 4; ++r) {
            int rl = ti * 16 + quad * 4 + r;
            float t1 = 0.f, t2 = 0.f;
            #pragma unroll
            for (int w8 = 0; w8 < 8; ++w8) { t1 += Ssum[rl][w8]; t2 += Ssq[rl][w8]; }
            float mu = t1 * (1.0f / DD);
            float var = t2 * (1.0f / DD) - mu * mu;
            float rs = rsqrtf(var + 1e-5f);
            #pragma unroll
            for (int tj = 0; tj < 2; ++tj) {
                int colb = wave * 32 + tj * 16 + lo;
                Tn[rl * TSTR + colb] =
                    f2bfs((vv[ti][tj][r] - mu) * rs * ln2w[colb] + ln2b[colb]);
            }
        }
    __syncthreads();   // Hn (in Tn) complete

    // ================= phase 1: a1 = Hn @ w1, K=256; wave owns 16 cols ================
    floatx4 a1[2];
    a1[0] = floatx4{0,0,0,0}; a1[1] = floatx4{0,0,0,0};
    for (int k0 = 0; k0 < 256; k0 += 64) {
        #pragma unroll
        for (int kk = 0; kk < 2; ++kk) {
            const int kof = k0 + kk * 32 + kq;
            short8 af[2], bfr;
            #pragma unroll
            for (int t = 0; t < 2; ++t)
                af[t] = *(const short8*)(&Tn[(t * 16 + lo) * TSTR + kof]);
            bfr = *(const short8*)(W1p + (size_t)(wave * 16 + lo) * 256 + kof);
            #pragma unroll
            for (int ti = 0; ti < 2; ++ti)
                a1[ti] = __builtin_amdgcn_mfma_f32_16x16x32_bf16(af[ti], bfr, a1[ti], 0, 0, 0);
        }
    }
    // gelu -> Hf (wave's 16 cols)
    {
        int colb = wave * 16 + lo;
        float bs = b1[colb];
        #pragma unroll
        for (int ti = 0; ti < 2; ++ti)
            #pragma unroll
            for (int r = 0; r < 4; ++r) {
                int rl = ti * 16 + quad * 4 + r;
                float v = a1[ti][r] + bs;
                v = 0.5f * v * (1.0f + erff(v * 0.70710678118f));
                Hf[rl * HSTR + colb] = f2bfs(v);
            }
    }
    __syncthreads();   // Hf complete

    // ================= phase 2: a2 = Hf @ w2, K=128; wave owns 32 cols ================
    floatx4 a2[2][2];
    #pragma unroll
    for (int i = 0; i < 2; ++i) { a2[i][0] = floatx4{0,0,0,0}; a2[i][1] = floatx4{0,0,0,0}; }
    for (int k0 = 0; k0 < 128; k0 += 64) {
        #pragma unroll
        for (int kk = 0; kk < 2; ++kk) {
            const int kof = k0 + kk * 32 + kq;
            short8 af[2], bfr[2];
            #pragma unroll
            for (int t = 0; t < 2; ++t)
                af[t] = *(const short8*)(&Hf[(t * 16 + lo) * HSTR + kof]);
            #pragma unroll
            for (int t = 0; t < 2; ++t)
                bfr[t] = *(const short8*)(W2p + (size_t)(wave * 32 + t * 16 + lo) * 128 + kof);
            #pragma unroll
            for (int ti = 0; ti < 2; ++ti)
                #pragma unroll
                for (int tj = 0; tj < 2; ++tj)
                    a2[ti][tj] = __builtin_amdgcn_mfma_f32_16x16x32_bf16(af[ti], bfr[tj], a2[ti][tj], 0, 0, 0);
        }
    }

    // ================= final: X = Y + FFN; opt LN1_next -> Xn =================
    #pragma unroll
    for (int ti = 0; ti < 2; ++ti)
        #pragma unroll
        for (int tj = 0; tj < 2; ++tj) {
            int colb = wave * 32 + tj * 16 + lo;
            float bs = b2[colb];
            #pragma unroll
            for (int r = 0; r < 4; ++r) {
                int row = row0 + ti * 16 + quad * 4 + r;
                float v = a2[ti][tj][r] + bs + vv[ti][tj][r];
                X[(size_t)row * DD + colb] = v;
                vv[ti][tj][r] = v;
            }
        }
    if (!DOLN) return;
    #pragma unroll
    for (int ti = 0; ti < 2; ++ti)
        #pragma unroll
        for (int r = 0; r < 4; ++r) {
            float s1 = 0.f, s2 = 0.f;
            #pragma unroll
            for (int tj = 0; tj < 2; ++tj) {
                float v = vv[ti][tj][r];
                s1 += v; s2 += v * v;
            }
            #pragma unroll
            for (int off = 1; off < 16; off <<= 1) {
                s1 += __shfl_xor(s1, off);
                s2 += __shfl_xor(s2, off);
            }
            if (lo == 0) {
                int rl = ti * 16 + quad * 4 + r;
                Ssum[rl][wave] = s1;
                Ssq[rl][wave] = s2;
            }
        }
    __syncthreads();
    #pragma unroll
    for (int ti = 0; ti < 2; ++ti)
        #pragma unroll
        for (int r = 0; r < 4; ++r) {
            int rl = ti * 16 + quad * 4 + r;
            float t1 = 0.f, t2 = 0.f;
            #pragma unroll
            for (int w8 = 0; w8 < 8; ++w8) { t1 += Ssum[rl][w8]; t2 += Ssq[rl][w8]; }
            float mu = t1 * (1.0f / DD);
            float var = t2 * (1.0f / DD) - mu * mu;
            float rs = rsqrtf(var + 1e-5f);
            int row = row0 + rl;
            #pragma unroll
            for (int tj = 0; tj < 2; ++tj) {
                int colb = wave * 32 + tj * 16 + lo;
                Xn[(size_t)row * DD + colb] =
                    f2bfs((vv[ti][tj][r] - mu) * rs * ln1w[colb] + ln1b[colb]);
            }
        }
}

extern "C" void kernel_launch(void* const* d_in, const int* in_sizes, int n_in,
                              void* d_out, int out_size, void* d_ws, size_t ws_size,
                              hipStream_t stream) {
    const int*   v    = (const int*)d_in[0];
    const float* emb  = (const float*)d_in[1];
    const float* WQ   = (const float*)d_in[2];
    const float* WK   = (const float*)d_in[3];
    const float* WV   = (const float*)d_in[4];
    const float* WG   = (const float*)d_in[5];
    const float* WO   = (const float*)d_in[6];
    const float* gn_w = (const float*)d_in[7];
    const float* gn_b = (const float*)d_in[8];
    const float* ln1w = (const float*)d_in[9];
    const float* ln1b = (const float*)d_in[10];
    const float* ln2w = (const float*)d_in[11];
    const float* ln2b = (const float*)d_in[12];
    const float* w1   = (const float*)d_in[13];
    const float* b1   = (const float*)d_in[14];
    const float* w2   = (const float*)d_in[15];
    const float* b2   = (const float*)d_in[16];

    float* X = (float*)d_out;                    // residual stream (f32) in d_out

    float* base  = (float*)d_ws;
    int*   flag  = (int*)base;
    short* Xn    = (short*)(base + 16);          // NROWS*256 bf16
    bf16*  QKVG  = (bf16*)(Xn + (size_t)NROWS * 256);  // NROWS*1024
    bf16*  WqkvgP = QKVG + (size_t)NROWS * 1024; // 3*1024*256
    bf16*  WoP   = WqkvgP + 3 * 1024 * 256;      // 3*256*256
    bf16*  W1P   = WoP + 3 * 256 * 256;          // 3*128*256
    bf16*  W2P   = W1P + 3 * 128 * 256;          // 3*256*128
    float4* xpt  = (float4*)(W2P + 3 * 256 * 128); // 512*16 float4

    // setup_pack also zeroes flag (stream-ordered before detect_v's atomicOr)
    setup_pack<<<NSETUP / 256, 256, 0, stream>>>(WQ, WK, WV, WG, WO, w1, w2,
                                                 WqkvgP, WoP, W1P, W2P, xpt, flag);
    detect_v<<<32, 256, 0, stream>>>(v, flag);
    // X = relu(emb[v]); Xn = LN1_0(X); 8 rows/block
    embed_ln_kernel<<<NROWS / 8, 256, 0, stream>>>(v, emb, flag, ln1w, ln1b, X, Xn);

    for (int i = 0; i < 3; ++i) {
        // QKVG = xpos(Xn @ [WQ|WK|WV|WG])
        qkvg_gemm<<<dim3(128, 8), 256, 0, stream>>>(Xn,
                                                    (const short*)(WqkvgP + (size_t)i * 1024 * 256),
                                                    xpt, QKVG);
        // mega-fused: retention(8 heads, 1/wave) -> T in LDS -> WO -> LN2 -> FFN -> X, Xn
        if (i < 2)
            ret_wo_ffn<1><<<512, 512, 0, stream>>>(QKVG, gn_w + i * DD, gn_b + i * DD,
                                                   (const short*)(WoP + (size_t)i * 256 * 256),
                                                   (const short*)(W1P + (size_t)i * 128 * 256),
                                                   b1 + i * FFNN,
                                                   (const short*)(W2P + (size_t)i * 256 * 128),
                                                   b2 + i * DD, X,
                                                   ln2w + i * DD, ln2b + i * DD,
                                                   ln1w + (i + 1) * DD, ln1b + (i + 1) * DD, Xn);
        else
            ret_wo_ffn<0><<<512, 512, 0, stream>>>(QKVG, gn_w + i * DD, gn_b + i * DD,
                                                   (const short*)(WoP + (size_t)i * 256 * 256),
                                                   (const short*)(W1P + (size_t)i * 128 * 256),
                                                   b1 + i * FFNN,
                                                   (const short*)(W2P + (size_t)i * 256 * 128),
                                                   b2 + i * DD, X,
                                                   ln2w + i * DD, ln2b + i * DD,
                                                   nullptr, nullptr, nullptr);
    }
}